// Round 1
// baseline (10792.067 us; speedup 1.0000x reference)
//
#include <hip/hip_runtime.h>
#include <cstdint>
#include <cstddef>

// Problem constants
static constexpr int BB = 64;    // batch
static constexpr int TT = 1024;  // time steps
static constexpr int FF = 512;   // input features
static constexpr int UU = 256;   // hidden units per direction
static constexpr int NZ = 1024;  // 4*UU gate width

// ---------------------------------------------------------------------------
// Pack U [UU, 4*UU] (row-major, gate blocks i|f|g|o along columns) into
// gate-interleaved float4: Upk[d][k][j] = {U[k][j], U[k][256+j], U[k][512+j], U[k][768+j]}
// ---------------------------------------------------------------------------
__global__ __launch_bounds__(256) void enc_pack_u(
    const float* __restrict__ Uf, const float* __restrict__ Ub,
    float4* __restrict__ Upk)
{
    int idx = blockIdx.x * 256 + threadIdx.x;
    if (idx >= 2 * UU * UU) return;
    int d = idx / (UU * UU);
    int rem = idx - d * (UU * UU);
    int k = rem / UU;
    int j = rem - k * UU;
    const float* Us = d ? Ub : Uf;
    const float* row = Us + (size_t)k * NZ;
    Upk[idx] = make_float4(row[j], row[UU + j], row[2 * UU + j], row[3 * UU + j]);
}

__global__ __launch_bounds__(256) void enc_zero(float* __restrict__ p, int n)
{
    int i = blockIdx.x * 256 + threadIdx.x;
    if (i < n) p[i] = 0.f;
}

// ---------------------------------------------------------------------------
// GEMM: xz[r, n] = x_row(r) . W_d[:, n] + b_d[n]
// rows r = (d*64 + b)*CT + tl  (chunk-local), M = 2*64*CT, N = 1024, K = 512
// 128x128 tile, K-step 8, 256 threads, 8x8 per-thread micro-tile (fp32)
// ---------------------------------------------------------------------------
__global__ __launch_bounds__(256) void enc_gemm_xz(
    const float* __restrict__ x,
    const float* __restrict__ Wf, const float* __restrict__ bf,
    const float* __restrict__ Wb, const float* __restrict__ bb,
    float* __restrict__ xz, int c0, int CT)
{
    __shared__ float As[8][132];
    __shared__ float Bs[8][132];

    const int tid = threadIdx.x;
    const int r0 = blockIdx.x * 128;       // row tile base
    const int n0 = blockIdx.y * 128;       // col tile base
    const int MperD = BB * CT;

    const int d = r0 / MperD;              // uniform across tile (MperD % 128 == 0 for CT>=2)
    const float* Wd = d ? Wb : Wf;
    const float* bd = d ? bb : bf;

    // x staging mapping: 2 threads per row
    const int srow = tid >> 1;             // 0..127
    const int q = tid & 1;                 // which half of 8-k chunk
    {
        // nothing
    }
    const int r = r0 + srow;
    const int rd = r - d * MperD;
    const int bidx = rd / CT;
    const int tl = rd - bidx * CT;
    const int tsrc = d ? (TT - 1 - (c0 + tl)) : (c0 + tl);
    const float* xrow = x + ((size_t)bidx * TT + tsrc) * FF;

    // W staging mapping
    const int wkk = tid >> 5;              // 0..7
    const int wj = (tid & 31) * 4;         // 0..124

    const int ty = tid >> 4;               // 0..15
    const int tx = tid & 15;               // 0..15

    float acc[8][8];
#pragma unroll
    for (int i = 0; i < 8; ++i)
#pragma unroll
        for (int j = 0; j < 8; ++j) acc[i][j] = 0.f;

    for (int k0 = 0; k0 < FF; k0 += 8) {
        float4 xv = *(const float4*)(xrow + k0 + q * 4);
        float4 wv = *(const float4*)(Wd + (size_t)(k0 + wkk) * NZ + n0 + wj);
        __syncthreads();   // previous iteration's LDS reads complete
        As[q * 4 + 0][srow] = xv.x;
        As[q * 4 + 1][srow] = xv.y;
        As[q * 4 + 2][srow] = xv.z;
        As[q * 4 + 3][srow] = xv.w;
        *(float4*)&Bs[wkk][wj] = wv;
        __syncthreads();
#pragma unroll
        for (int kk = 0; kk < 8; ++kk) {
            float a[8], bv[8];
            *(float4*)&a[0]  = *(const float4*)&As[kk][ty * 8];
            *(float4*)&a[4]  = *(const float4*)&As[kk][ty * 8 + 4];
            *(float4*)&bv[0] = *(const float4*)&Bs[kk][tx * 8];
            *(float4*)&bv[4] = *(const float4*)&Bs[kk][tx * 8 + 4];
#pragma unroll
            for (int i = 0; i < 8; ++i)
#pragma unroll
                for (int j = 0; j < 8; ++j)
                    acc[i][j] = fmaf(a[i], bv[j], acc[i][j]);
        }
    }

    // epilogue: add bias, store
    float bias[8];
#pragma unroll
    for (int j = 0; j < 8; ++j) bias[j] = bd[n0 + tx * 8 + j];
#pragma unroll
    for (int i = 0; i < 8; ++i) {
        int rr = r0 + ty * 8 + i;
        float4 o0, o1;
        o0.x = acc[i][0] + bias[0]; o0.y = acc[i][1] + bias[1];
        o0.z = acc[i][2] + bias[2]; o0.w = acc[i][3] + bias[3];
        o1.x = acc[i][4] + bias[4]; o1.y = acc[i][5] + bias[5];
        o1.z = acc[i][6] + bias[6]; o1.w = acc[i][7] + bias[7];
        float* op = xz + (size_t)rr * NZ + n0 + tx * 8;
        *(float4*)(op)     = o0;
        *(float4*)(op + 4) = o1;
    }
}

// ---------------------------------------------------------------------------
// Recurrence over a chunk of CT steps. One block per (dir, batch-pair).
// 256 threads; thread t owns hidden column t for both batches of the pair.
// ---------------------------------------------------------------------------
__device__ __forceinline__ float sigm_f(float xv)
{
    return 1.0f / (1.0f + __expf(-xv));
}
__device__ __forceinline__ float tanh_f(float xv)
{
    // tanh(x) = 2/(1+e^{-2x}) - 1
    return 2.0f / (1.0f + __expf(-2.0f * xv)) - 1.0f;
}

__global__ __launch_bounds__(256) void enc_lstm_chunk(
    const float* __restrict__ xz, const float4* __restrict__ Upk,
    float* __restrict__ hstate, float* __restrict__ cstate,
    float* __restrict__ out, int c0, int CT)
{
    __shared__ __align__(16) float h0[UU];
    __shared__ __align__(16) float h1[UU];

    const int tid = threadIdx.x;           // hidden column
    const int d = blockIdx.x >> 5;
    const int g = blockIdx.x & 31;
    const int b0i = g * 2;
    const int b1i = g * 2 + 1;

    const int s0 = (d * BB + b0i) * UU + tid;
    const int s1 = (d * BB + b1i) * UU + tid;
    float c0r = cstate[s0];
    float c1r = cstate[s1];
    h0[tid] = hstate[s0];
    h1[tid] = hstate[s1];

    const float4* Ud = Upk + (size_t)d * UU * UU;
    const float* xz0 = xz + (size_t)(d * BB + b0i) * CT * NZ;
    const float* xz1 = xz + (size_t)(d * BB + b1i) * CT * NZ;

    __syncthreads();

    for (int tl = 0; tl < CT; ++tl) {
        const float* p0 = xz0 + (size_t)tl * NZ;
        const float* p1 = xz1 + (size_t)tl * NZ;
        float zi0 = p0[tid], zf0 = p0[UU + tid], zg0 = p0[2 * UU + tid], zo0 = p0[3 * UU + tid];
        float zi1 = p1[tid], zf1 = p1[UU + tid], zg1 = p1[2 * UU + tid], zo1 = p1[3 * UU + tid];

#pragma unroll 4
        for (int k4 = 0; k4 < UU / 4; ++k4) {
            float4 ha = *(const float4*)&h0[k4 * 4];
            float4 hb = *(const float4*)&h1[k4 * 4];
            float4 u0 = Ud[(size_t)(k4 * 4 + 0) * UU + tid];
            float4 u1 = Ud[(size_t)(k4 * 4 + 1) * UU + tid];
            float4 u2 = Ud[(size_t)(k4 * 4 + 2) * UU + tid];
            float4 u3 = Ud[(size_t)(k4 * 4 + 3) * UU + tid];

            zi0 = fmaf(ha.x, u0.x, zi0); zf0 = fmaf(ha.x, u0.y, zf0);
            zg0 = fmaf(ha.x, u0.z, zg0); zo0 = fmaf(ha.x, u0.w, zo0);
            zi1 = fmaf(hb.x, u0.x, zi1); zf1 = fmaf(hb.x, u0.y, zf1);
            zg1 = fmaf(hb.x, u0.z, zg1); zo1 = fmaf(hb.x, u0.w, zo1);

            zi0 = fmaf(ha.y, u1.x, zi0); zf0 = fmaf(ha.y, u1.y, zf0);
            zg0 = fmaf(ha.y, u1.z, zg0); zo0 = fmaf(ha.y, u1.w, zo0);
            zi1 = fmaf(hb.y, u1.x, zi1); zf1 = fmaf(hb.y, u1.y, zf1);
            zg1 = fmaf(hb.y, u1.z, zg1); zo1 = fmaf(hb.y, u1.w, zo1);

            zi0 = fmaf(ha.z, u2.x, zi0); zf0 = fmaf(ha.z, u2.y, zf0);
            zg0 = fmaf(ha.z, u2.z, zg0); zo0 = fmaf(ha.z, u2.w, zo0);
            zi1 = fmaf(hb.z, u2.x, zi1); zf1 = fmaf(hb.z, u2.y, zf1);
            zg1 = fmaf(hb.z, u2.z, zg1); zo1 = fmaf(hb.z, u2.w, zo1);

            zi0 = fmaf(ha.w, u3.x, zi0); zf0 = fmaf(ha.w, u3.y, zf0);
            zg0 = fmaf(ha.w, u3.z, zg0); zo0 = fmaf(ha.w, u3.w, zo0);
            zi1 = fmaf(hb.w, u3.x, zi1); zf1 = fmaf(hb.w, u3.y, zf1);
            zg1 = fmaf(hb.w, u3.z, zg1); zo1 = fmaf(hb.w, u3.w, zo1);
        }

        // gates
        float i0 = sigm_f(zi0), f0 = sigm_f(zf0), gg0 = tanh_f(zg0), o0 = sigm_f(zo0);
        float i1 = sigm_f(zi1), f1 = sigm_f(zf1), gg1 = tanh_f(zg1), o1 = sigm_f(zo1);
        c0r = f0 * c0r + i0 * gg0;
        c1r = f1 * c1r + i1 * gg1;
        float hn0 = o0 * tanh_f(c0r);
        float hn1 = o1 * tanh_f(c1r);

        int tsrc = d ? (TT - 1 - (c0 + tl)) : (c0 + tl);
        out[((size_t)b0i * TT + tsrc) * (2 * UU) + d * UU + tid] = hn0;
        out[((size_t)b1i * TT + tsrc) * (2 * UU) + d * UU + tid] = hn1;

        __syncthreads();   // everyone done reading h
        h0[tid] = hn0;
        h1[tid] = hn1;
        __syncthreads();   // new h visible
    }

    cstate[s0] = c0r;
    cstate[s1] = c1r;
    hstate[s0] = h0[tid];
    hstate[s1] = h1[tid];
}

// ---------------------------------------------------------------------------
// Final h/c copy into d_out tail sections
// ---------------------------------------------------------------------------
__global__ __launch_bounds__(256) void enc_final(
    const float* __restrict__ hstate, const float* __restrict__ cstate,
    float* __restrict__ out)
{
    int idx = blockIdx.x * 256 + threadIdx.x;
    if (idx >= 2 * BB * UU) return;
    int d = idx / (BB * UU);
    int rem = idx - d * (BB * UU);
    int b = rem / UU;
    int j = rem - b * UU;
    size_t OUT_H = (size_t)BB * TT * (2 * UU);
    size_t HSZ = (size_t)BB * (2 * UU);
    out[OUT_H + (size_t)b * (2 * UU) + d * UU + j] = hstate[idx];
    out[OUT_H + HSZ + (size_t)b * (2 * UU) + d * UU + j] = cstate[idx];
}

// ---------------------------------------------------------------------------
extern "C" void kernel_launch(void* const* d_in, const int* in_sizes, int n_in,
                              void* d_out, int out_size, void* d_ws, size_t ws_size,
                              hipStream_t stream)
{
    const float* x  = (const float*)d_in[0];
    const float* Wf = (const float*)d_in[1];
    const float* Uf = (const float*)d_in[2];
    const float* bf = (const float*)d_in[3];
    const float* Wb = (const float*)d_in[4];
    const float* Ub = (const float*)d_in[5];
    const float* bb = (const float*)d_in[6];
    float* out = (float*)d_out;

    const size_t upk_bytes   = (size_t)2 * UU * UU * sizeof(float4); // 2 MiB
    const size_t state_bytes = (size_t)2 * BB * UU * sizeof(float);  // 128 KiB each

    int CT = TT;
    while (CT > 8) {
        size_t need = (size_t)2 * BB * CT * NZ * sizeof(float) + upk_bytes + 2 * state_bytes;
        if (need <= ws_size) break;
        CT >>= 1;
    }

    char* wsb = (char*)d_ws;
    float* xz = (float*)wsb;
    size_t xz_bytes = (size_t)2 * BB * CT * NZ * sizeof(float);
    float4* Upk = (float4*)(wsb + xz_bytes);
    float* hstate = (float*)(wsb + xz_bytes + upk_bytes);
    float* cstate = hstate + 2 * BB * UU;

    enc_pack_u<<<(2 * UU * UU + 255) / 256, 256, 0, stream>>>(Uf, Ub, Upk);
    enc_zero<<<(2 * 2 * BB * UU + 255) / 256, 256, 0, stream>>>(hstate, 2 * 2 * BB * UU);

    for (int c0 = 0; c0 < TT; c0 += CT) {
        dim3 ggrid((2 * BB * CT) / 128, NZ / 128);
        enc_gemm_xz<<<ggrid, 256, 0, stream>>>(x, Wf, bf, Wb, bb, xz, c0, CT);
        enc_lstm_chunk<<<64, 256, 0, stream>>>(xz, Upk, hstate, cstate, out, c0, CT);
    }
    enc_final<<<(2 * BB * UU + 255) / 256, 256, 0, stream>>>(hstate, cstate, out);
}

// Round 2
// 3167.482 us; speedup vs baseline: 3.4071x; 3.4071x over previous
//
#include <hip/hip_runtime.h>
#include <cstdint>
#include <cstddef>

typedef _Float16 f16x2 __attribute__((ext_vector_type(2)));

static constexpr int BB = 64;    // batch
static constexpr int TT = 1024;  // time steps
static constexpr int FF = 512;   // input features
static constexpr int UU = 256;   // hidden units per direction
static constexpr int NZ = 1024;  // 4*UU gate width

static constexpr int LSTM_THREADS = 512;
static constexpr int REG_K2 = 48;                 // k2-pairs held in VGPRs per thread
static constexpr int LDS_K2 = 16;                 // k2-pairs held in LDS per thread
static constexpr size_t LDSU_BYTES = (size_t)LDS_K2 * 512 * 16;     // 128 KiB
static constexpr size_t PART_BYTES = 256 * 16;                      // 4 KiB
static constexpr size_t HSH_BYTES  = 512;                           // 256 f16
static constexpr size_t LSTM_SHBYTES = LDSU_BYTES + PART_BYTES + HSH_BYTES;

__device__ __forceinline__ f16x2 bc16(unsigned int v) { return __builtin_bit_cast(f16x2, v); }

// ---------------------------------------------------------------------------
// Pack U [UU, 4*UU] fp32 into f16x2 dot2-friendly layout:
// Upkr[(d*64 + k2l)*512 + t] = uint4 of 4 gate words; t = s*256 + j,
// word g = { U_d[k][g*256+j], U_d[k+1][g*256+j] } f16x2, k = s*128 + 2*k2l.
// ---------------------------------------------------------------------------
__global__ __launch_bounds__(256) void enc_pack_u16(
    const float* __restrict__ Uf, const float* __restrict__ Ub,
    uint4* __restrict__ Upkr)
{
    int idx = blockIdx.x * 256 + threadIdx.x;     // 0 .. 65535
    if (idx >= 2 * 64 * 512) return;
    int d   = idx >> 15;
    int rem = idx & 32767;
    int k2l = rem >> 9;                           // 0..63
    int t   = rem & 511;
    int s = t >> 8, j = t & 255;
    int k = s * 128 + 2 * k2l;
    const float* Ud = d ? Ub : Uf;
    unsigned int w[4];
#pragma unroll
    for (int g = 0; g < 4; ++g) {
        f16x2 h;
        h.x = (_Float16)Ud[(size_t)k * NZ + g * 256 + j];
        h.y = (_Float16)Ud[(size_t)(k + 1) * NZ + g * 256 + j];
        w[g] = __builtin_bit_cast(unsigned int, h);
    }
    Upkr[idx] = make_uint4(w[0], w[1], w[2], w[3]);
}

__global__ __launch_bounds__(256) void enc_zero(float* __restrict__ p, int n)
{
    int i = blockIdx.x * 256 + threadIdx.x;
    if (i < n) p[i] = 0.f;
}

// ---------------------------------------------------------------------------
// GEMM: xz[r, n] = x_row(r) . W_d[:, n] + b_d[n]   (unchanged from R1)
// ---------------------------------------------------------------------------
__global__ __launch_bounds__(256) void enc_gemm_xz(
    const float* __restrict__ x,
    const float* __restrict__ Wf, const float* __restrict__ bf,
    const float* __restrict__ Wb, const float* __restrict__ bb,
    float* __restrict__ xz, int c0, int CT)
{
    __shared__ float As[8][132];
    __shared__ float Bs[8][132];

    const int tid = threadIdx.x;
    const int r0 = blockIdx.x * 128;
    const int n0 = blockIdx.y * 128;
    const int MperD = BB * CT;

    const int d = r0 / MperD;
    const float* Wd = d ? Wb : Wf;
    const float* bd = d ? bb : bf;

    const int srow = tid >> 1;
    const int q = tid & 1;
    const int r = r0 + srow;
    const int rd = r - d * MperD;
    const int bidx = rd / CT;
    const int tl = rd - bidx * CT;
    const int tsrc = d ? (TT - 1 - (c0 + tl)) : (c0 + tl);
    const float* xrow = x + ((size_t)bidx * TT + tsrc) * FF;

    const int wkk = tid >> 5;
    const int wj = (tid & 31) * 4;

    const int ty = tid >> 4;
    const int tx = tid & 15;

    float acc[8][8];
#pragma unroll
    for (int i = 0; i < 8; ++i)
#pragma unroll
        for (int j = 0; j < 8; ++j) acc[i][j] = 0.f;

    for (int k0 = 0; k0 < FF; k0 += 8) {
        float4 xv = *(const float4*)(xrow + k0 + q * 4);
        float4 wv = *(const float4*)(Wd + (size_t)(k0 + wkk) * NZ + n0 + wj);
        __syncthreads();
        As[q * 4 + 0][srow] = xv.x;
        As[q * 4 + 1][srow] = xv.y;
        As[q * 4 + 2][srow] = xv.z;
        As[q * 4 + 3][srow] = xv.w;
        *(float4*)&Bs[wkk][wj] = wv;
        __syncthreads();
#pragma unroll
        for (int kk = 0; kk < 8; ++kk) {
            float a[8], bv[8];
            *(float4*)&a[0]  = *(const float4*)&As[kk][ty * 8];
            *(float4*)&a[4]  = *(const float4*)&As[kk][ty * 8 + 4];
            *(float4*)&bv[0] = *(const float4*)&Bs[kk][tx * 8];
            *(float4*)&bv[4] = *(const float4*)&Bs[kk][tx * 8 + 4];
#pragma unroll
            for (int i = 0; i < 8; ++i)
#pragma unroll
                for (int j = 0; j < 8; ++j)
                    acc[i][j] = fmaf(a[i], bv[j], acc[i][j]);
        }
    }

    float bias[8];
#pragma unroll
    for (int j = 0; j < 8; ++j) bias[j] = bd[n0 + tx * 8 + j];
#pragma unroll
    for (int i = 0; i < 8; ++i) {
        int rr = r0 + ty * 8 + i;
        float4 o0, o1;
        o0.x = acc[i][0] + bias[0]; o0.y = acc[i][1] + bias[1];
        o0.z = acc[i][2] + bias[2]; o0.w = acc[i][3] + bias[3];
        o1.x = acc[i][4] + bias[4]; o1.y = acc[i][5] + bias[5];
        o1.z = acc[i][6] + bias[6]; o1.w = acc[i][7] + bias[7];
        float* op = xz + (size_t)rr * NZ + n0 + tx * 8;
        *(float4*)(op)     = o0;
        *(float4*)(op + 4) = o1;
    }
}

// ---------------------------------------------------------------------------
// Persistent-U recurrence. One block per (dir, batch) chain, 512 threads.
// Thread t = (s, j): s = k-half (0/1), j = hidden unit. U f16: 48 k2-pairs
// in VGPRs + 16 k2-pairs in LDS per thread. h in LDS as f16.
// ---------------------------------------------------------------------------
__device__ __forceinline__ float sigm_f(float xv)
{
    return 1.0f / (1.0f + __expf(-xv));
}
__device__ __forceinline__ float tanh_f(float xv)
{
    return 2.0f / (1.0f + __expf(-2.0f * xv)) - 1.0f;
}

__global__ __launch_bounds__(LSTM_THREADS, 2) void enc_lstm_persist(
    const float* __restrict__ xz, const uint4* __restrict__ Upkr,
    float* __restrict__ hstate, float* __restrict__ cstate,
    float* __restrict__ out, int c0, int CT)
{
    extern __shared__ char smem[];
    uint4*     ldsu = (uint4*)smem;                                   // 128 KiB
    float4*    part = (float4*)(smem + LDSU_BYTES);                   // 4 KiB
    _Float16*  hsh  = (_Float16*)(smem + LDSU_BYTES + PART_BYTES);    // 512 B
    uint4*     hshq = (uint4*)hsh;

    const int t = threadIdx.x;
    const int s = t >> 8;
    const int j = t & 255;
    const int bi = blockIdx.x;
    const int d = bi >> 6;
    const int b = bi & 63;

    // ---- load persistent U ----
    const uint4* Uq = Upkr + (size_t)d * 64 * 512;
    f16x2 ureg[REG_K2][4];
#pragma unroll
    for (int k2l = 0; k2l < REG_K2; ++k2l) {
        uint4 qv = Uq[(size_t)k2l * 512 + t];
        ureg[k2l][0] = bc16(qv.x);
        ureg[k2l][1] = bc16(qv.y);
        ureg[k2l][2] = bc16(qv.z);
        ureg[k2l][3] = bc16(qv.w);
    }
#pragma unroll
    for (int k2l = REG_K2; k2l < 64; ++k2l)
        ldsu[(size_t)(k2l - REG_K2) * 512 + t] = Uq[(size_t)k2l * 512 + t];

    // ---- state init ----
    float c = 0.f;
    if (s == 0) c = cstate[(size_t)(d * BB + b) * UU + j];
    if (t < 256) hsh[t] = (_Float16)hstate[(size_t)(d * BB + b) * UU + t];
    __syncthreads();

    const float* xzrow = xz + (size_t)(d * BB + b) * CT * NZ;
    float* outb = out + (size_t)b * TT * (2 * UU) + d * UU;

    float hn = 0.f;
    for (int tl = 0; tl < CT; ++tl) {
        float x0 = 0.f, x1 = 0.f, x2 = 0.f, x3 = 0.f;
        if (s == 0) {
            const float* p = xzrow + (size_t)tl * NZ + j;
            x0 = p[0]; x1 = p[256]; x2 = p[512]; x3 = p[768];
        }

        float a0 = 0.f, a1 = 0.f, a2 = 0.f, a3 = 0.f;
#pragma unroll
        for (int k2b = 0; k2b < 16; ++k2b) {
            uint4 hq = hshq[s * 16 + k2b];
            f16x2 hw0 = bc16(hq.x), hw1 = bc16(hq.y), hw2 = bc16(hq.z), hw3 = bc16(hq.w);
            f16x2 hw[4] = {hw0, hw1, hw2, hw3};
#pragma unroll
            for (int r = 0; r < 4; ++r) {
                const int k2l = k2b * 4 + r;
                f16x2 u0, u1, u2, u3;
                if (k2l < REG_K2) {
                    u0 = ureg[k2l][0]; u1 = ureg[k2l][1];
                    u2 = ureg[k2l][2]; u3 = ureg[k2l][3];
                } else {
                    uint4 uq = ldsu[(size_t)(k2l - REG_K2) * 512 + t];
                    u0 = bc16(uq.x); u1 = bc16(uq.y); u2 = bc16(uq.z); u3 = bc16(uq.w);
                }
                a0 = __builtin_amdgcn_fdot2(hw[r], u0, a0, false);
                a1 = __builtin_amdgcn_fdot2(hw[r], u1, a1, false);
                a2 = __builtin_amdgcn_fdot2(hw[r], u2, a2, false);
                a3 = __builtin_amdgcn_fdot2(hw[r], u3, a3, false);
            }
        }

        if (s == 1) part[j] = make_float4(a0, a1, a2, a3);
        __syncthreads();

        if (s == 0) {
            float4 pr = part[j];
            float zi = a0 + pr.x + x0;
            float zf = a1 + pr.y + x1;
            float zg = a2 + pr.z + x2;
            float zo = a3 + pr.w + x3;
            float ig = sigm_f(zi), fg = sigm_f(zf), gg = tanh_f(zg), og = sigm_f(zo);
            c = fg * c + ig * gg;
            hn = og * tanh_f(c);
            int tsrc = d ? (TT - 1 - (c0 + tl)) : (c0 + tl);
            outb[(size_t)tsrc * (2 * UU) + j] = hn;
            hsh[j] = (_Float16)hn;
        }
        __syncthreads();
    }

    if (s == 0) {
        hstate[(size_t)(d * BB + b) * UU + j] = hn;
        cstate[(size_t)(d * BB + b) * UU + j] = c;
    }
}

// ---------------------------------------------------------------------------
// Final h/c copy into d_out tail sections
// ---------------------------------------------------------------------------
__global__ __launch_bounds__(256) void enc_final(
    const float* __restrict__ hstate, const float* __restrict__ cstate,
    float* __restrict__ out)
{
    int idx = blockIdx.x * 256 + threadIdx.x;
    if (idx >= 2 * BB * UU) return;
    int d = idx / (BB * UU);
    int rem = idx - d * (BB * UU);
    int b = rem / UU;
    int j = rem - b * UU;
    size_t OUT_H = (size_t)BB * TT * (2 * UU);
    size_t HSZ = (size_t)BB * (2 * UU);
    out[OUT_H + (size_t)b * (2 * UU) + d * UU + j] = hstate[idx];
    out[OUT_H + HSZ + (size_t)b * (2 * UU) + d * UU + j] = cstate[idx];
}

// ---------------------------------------------------------------------------
extern "C" void kernel_launch(void* const* d_in, const int* in_sizes, int n_in,
                              void* d_out, int out_size, void* d_ws, size_t ws_size,
                              hipStream_t stream)
{
    const float* x  = (const float*)d_in[0];
    const float* Wf = (const float*)d_in[1];
    const float* Uf = (const float*)d_in[2];
    const float* bf = (const float*)d_in[3];
    const float* Wb = (const float*)d_in[4];
    const float* Ub = (const float*)d_in[5];
    const float* bb = (const float*)d_in[6];
    float* out = (float*)d_out;

    const size_t upk_bytes   = (size_t)2 * 64 * 512 * sizeof(uint4); // 1 MiB
    const size_t state_bytes = (size_t)2 * BB * UU * sizeof(float);  // 128 KiB each

    int CT = TT;
    while (CT > 8) {
        size_t need = (size_t)2 * BB * CT * NZ * sizeof(float) + upk_bytes + 2 * state_bytes;
        if (need <= ws_size) break;
        CT >>= 1;
    }

    char* wsb = (char*)d_ws;
    float* xz = (float*)wsb;
    size_t xz_bytes = (size_t)2 * BB * CT * NZ * sizeof(float);
    uint4* Upkr = (uint4*)(wsb + xz_bytes);
    float* hstate = (float*)(wsb + xz_bytes + upk_bytes);
    float* cstate = hstate + 2 * BB * UU;

    // allow >64KiB dynamic LDS for the persistent-U kernel
    (void)hipFuncSetAttribute(reinterpret_cast<const void*>(enc_lstm_persist),
                              hipFuncAttributeMaxDynamicSharedMemorySize,
                              (int)LSTM_SHBYTES);

    enc_pack_u16<<<(2 * 64 * 512 + 255) / 256, 256, 0, stream>>>(Uf, Ub, Upkr);
    enc_zero<<<(2 * 2 * BB * UU + 255) / 256, 256, 0, stream>>>(hstate, 2 * 2 * BB * UU);

    for (int c0 = 0; c0 < TT; c0 += CT) {
        dim3 ggrid((2 * BB * CT) / 128, NZ / 128);
        enc_gemm_xz<<<ggrid, 256, 0, stream>>>(x, Wf, bf, Wb, bb, xz, c0, CT);
        enc_lstm_persist<<<128, LSTM_THREADS, LSTM_SHBYTES, stream>>>(
            xz, Upkr, hstate, cstate, out, c0, CT);
    }
    enc_final<<<(2 * BB * UU + 255) / 256, 256, 0, stream>>>(hstate, cstate, out);
}

// Round 3
// 1916.860 us; speedup vs baseline: 5.6301x; 1.6524x over previous
//
#include <hip/hip_runtime.h>
#include <cstdint>
#include <cstddef>

typedef _Float16 f16x2 __attribute__((ext_vector_type(2)));
typedef _Float16 half4 __attribute__((ext_vector_type(4)));
typedef _Float16 half8 __attribute__((ext_vector_type(8)));
typedef float f32x4 __attribute__((ext_vector_type(4)));

static constexpr int BB = 64;    // batch
static constexpr int TT = 1024;  // time steps
static constexpr int FF = 512;   // input features
static constexpr int UU = 256;   // hidden units per direction
static constexpr int NZ = 1024;  // 4*UU gate width

static constexpr int LSTM_THREADS = 512;
static constexpr int REG_K2 = 48;                 // k2-pairs held in VGPRs per thread
static constexpr int LDS_K2 = 16;                 // k2-pairs held in LDS per thread
static constexpr size_t LDSU_BYTES = (size_t)LDS_K2 * 512 * 16;     // 128 KiB
static constexpr size_t PART_BYTES = 256 * 16;                      // 4 KiB
static constexpr size_t HSH_BYTES  = 512;                           // 256 f16
static constexpr size_t LSTM_SHBYTES = LDSU_BYTES + PART_BYTES + HSH_BYTES;

__device__ __forceinline__ f16x2 bc16(unsigned int v) { return __builtin_bit_cast(f16x2, v); }

// ---------------------------------------------------------------------------
// Cast x fp32 -> f16 (flat)
// ---------------------------------------------------------------------------
__global__ __launch_bounds__(256) void enc_cast_x(
    const float* __restrict__ x, _Float16* __restrict__ x16, int n4)
{
    int stride = gridDim.x * 256;
    for (int i = blockIdx.x * 256 + threadIdx.x; i < n4; i += stride) {
        float4 v = ((const float4*)x)[i];
        half4 o;
        o.x = (_Float16)v.x; o.y = (_Float16)v.y;
        o.z = (_Float16)v.z; o.w = (_Float16)v.w;
        ((half4*)x16)[i] = o;
    }
}

// ---------------------------------------------------------------------------
// W [512,1024] fp32 -> WT [dir][1024][512] f16 (transposed)
// grid (8, 16, 2): k-tile, n-tile, dir. 64x64 tiles via LDS.
// ---------------------------------------------------------------------------
__global__ __launch_bounds__(256) void enc_cast_wt(
    const float* __restrict__ Wf, const float* __restrict__ Wb,
    _Float16* __restrict__ WT)
{
    __shared__ float tile[64][65];
    const int t = threadIdx.x;
    const int k0 = blockIdx.x * 64;
    const int n0 = blockIdx.y * 64;
    const int d = blockIdx.z;
    const float* W = d ? Wb : Wf;
    _Float16* WTd = WT + (size_t)d * NZ * FF;
#pragma unroll
    for (int p = 0; p < 16; ++p) {
        int idx = p * 256 + t;
        int r = idx >> 6, c = idx & 63;
        tile[r][c] = W[(size_t)(k0 + r) * NZ + n0 + c];
    }
    __syncthreads();
#pragma unroll
    for (int p = 0; p < 16; ++p) {
        int idx = p * 256 + t;
        int r = idx >> 6, c = idx & 63;
        WTd[(size_t)(n0 + r) * FF + k0 + c] = (_Float16)tile[c][r];
    }
}

// ---------------------------------------------------------------------------
// Pack U [UU, 4*UU] fp32 into f16x2 dot2-friendly layout (unchanged from R2)
// ---------------------------------------------------------------------------
__global__ __launch_bounds__(256) void enc_pack_u16(
    const float* __restrict__ Uf, const float* __restrict__ Ub,
    uint4* __restrict__ Upkr)
{
    int idx = blockIdx.x * 256 + threadIdx.x;     // 0 .. 65535
    if (idx >= 2 * 64 * 512) return;
    int d   = idx >> 15;
    int rem = idx & 32767;
    int k2l = rem >> 9;                           // 0..63
    int t   = rem & 511;
    int s = t >> 8, j = t & 255;
    int k = s * 128 + 2 * k2l;
    const float* Ud = d ? Ub : Uf;
    unsigned int w[4];
#pragma unroll
    for (int g = 0; g < 4; ++g) {
        f16x2 h;
        h.x = (_Float16)Ud[(size_t)k * NZ + g * 256 + j];
        h.y = (_Float16)Ud[(size_t)(k + 1) * NZ + g * 256 + j];
        w[g] = __builtin_bit_cast(unsigned int, h);
    }
    Upkr[idx] = make_uint4(w[0], w[1], w[2], w[3]);
}

__global__ __launch_bounds__(256) void enc_zero(float* __restrict__ p, int n)
{
    int i = blockIdx.x * 256 + threadIdx.x;
    if (i < n) p[i] = 0.f;
}

// ---------------------------------------------------------------------------
// MFMA GEMM: xz16[r, n] = x16_row(r) . W_d[:, n] + b_d[n]   (f16 in, f16 out)
// 128x128 tile, BK=32, 256 threads (4 waves, 2x2), 4x4 16x16x32 frags/wave.
// ---------------------------------------------------------------------------
__global__ __launch_bounds__(256) void enc_gemm16(
    const _Float16* __restrict__ x16, const _Float16* __restrict__ WT,
    const float* __restrict__ bf, const float* __restrict__ bb,
    _Float16* __restrict__ xz16, int c0, int CT)
{
    __shared__ __align__(16) _Float16 Ash[128][40];
    __shared__ __align__(16) _Float16 Bsh[128][40];

    const int t = threadIdx.x;
    const int r0 = blockIdx.x * 128;
    const int n0 = blockIdx.y * 128;
    const int MperD = BB * CT;
    const int d = r0 / MperD;

    // staging addresses (fixed across k-steps)
    const int srow = t >> 2;            // 0..63
    const int koff = (t & 3) * 8;       // f16 offset within BK=32

    auto xrowptr = [&](int r) -> const _Float16* {
        int rd = r - d * MperD;
        int b = rd / CT;
        int tl = rd - b * CT;
        int tsrc = d ? (TT - 1 - (c0 + tl)) : (c0 + tl);
        return x16 + ((size_t)b * TT + tsrc) * FF;
    };
    const _Float16* ap0 = xrowptr(r0 + srow);
    const _Float16* ap1 = xrowptr(r0 + 64 + srow);
    const _Float16* wp0 = WT + (size_t)(d * NZ + n0 + srow) * FF;
    const _Float16* wp1 = wp0 + (size_t)64 * FF;

    const int lane = t & 63;
    const int w = t >> 6;
    const int wm = w >> 1, wn = w & 1;
    const int l15 = lane & 15;
    const int kq = (lane >> 4) * 8;

    f32x4 acc[4][4];
#pragma unroll
    for (int i = 0; i < 4; ++i)
#pragma unroll
        for (int j = 0; j < 4; ++j) acc[i][j] = (f32x4)0.f;

    for (int ks = 0; ks < FF / 32; ++ks) {
        const int k0 = ks * 32;
        uint4 av0 = *(const uint4*)(ap0 + k0 + koff);
        uint4 av1 = *(const uint4*)(ap1 + k0 + koff);
        uint4 bv0 = *(const uint4*)(wp0 + k0 + koff);
        uint4 bv1 = *(const uint4*)(wp1 + k0 + koff);
        __syncthreads();
        *(uint4*)&Ash[srow][koff]      = av0;
        *(uint4*)&Ash[64 + srow][koff] = av1;
        *(uint4*)&Bsh[srow][koff]      = bv0;
        *(uint4*)&Bsh[64 + srow][koff] = bv1;
        __syncthreads();

        half8 af[4], bfr[4];
#pragma unroll
        for (int mf = 0; mf < 4; ++mf)
            af[mf] = *(const half8*)&Ash[wm * 64 + mf * 16 + l15][kq];
#pragma unroll
        for (int nf = 0; nf < 4; ++nf)
            bfr[nf] = *(const half8*)&Bsh[wn * 64 + nf * 16 + l15][kq];
#pragma unroll
        for (int mf = 0; mf < 4; ++mf)
#pragma unroll
            for (int nf = 0; nf < 4; ++nf)
                acc[mf][nf] = __builtin_amdgcn_mfma_f32_16x16x32_f16(
                    af[mf], bfr[nf], acc[mf][nf], 0, 0, 0);
    }

    // epilogue: bias + f16 store
    const float* bd = d ? bb : bf;
    const int rbase = r0 + wm * 64;
    const int cbase = n0 + wn * 64;
#pragma unroll
    for (int nf = 0; nf < 4; ++nf) {
        const int cc = cbase + nf * 16 + l15;
        const float bia = bd[cc];
#pragma unroll
        for (int mf = 0; mf < 4; ++mf) {
#pragma unroll
            for (int rg = 0; rg < 4; ++rg) {
                int rr = rbase + mf * 16 + (lane >> 4) * 4 + rg;
                xz16[(size_t)rr * NZ + cc] = (_Float16)(acc[mf][nf][rg] + bia);
            }
        }
    }
}

// ---------------------------------------------------------------------------
// Persistent-U recurrence (f16 xz). One block per (dir, batch), 512 threads.
// ---------------------------------------------------------------------------
__device__ __forceinline__ float sigm_f(float xv)
{
    return 1.0f / (1.0f + __expf(-xv));
}
__device__ __forceinline__ float tanh_f(float xv)
{
    return 2.0f / (1.0f + __expf(-2.0f * xv)) - 1.0f;
}

__global__ __launch_bounds__(LSTM_THREADS, 2) void enc_lstm_persist(
    const _Float16* __restrict__ xz16, const uint4* __restrict__ Upkr,
    float* __restrict__ hstate, float* __restrict__ cstate,
    float* __restrict__ out, int c0, int CT)
{
    extern __shared__ char smem[];
    uint4*     ldsu = (uint4*)smem;                                   // 128 KiB
    float4*    part = (float4*)(smem + LDSU_BYTES);                   // 4 KiB
    _Float16*  hsh  = (_Float16*)(smem + LDSU_BYTES + PART_BYTES);    // 512 B
    uint4*     hshq = (uint4*)hsh;

    const int t = threadIdx.x;
    const int s = t >> 8;
    const int j = t & 255;
    const int bi = blockIdx.x;
    const int d = bi >> 6;
    const int b = bi & 63;

    // ---- load persistent U ----
    const uint4* Uq = Upkr + (size_t)d * 64 * 512;
    f16x2 ureg[REG_K2][4];
#pragma unroll
    for (int k2l = 0; k2l < REG_K2; ++k2l) {
        uint4 qv = Uq[(size_t)k2l * 512 + t];
        ureg[k2l][0] = bc16(qv.x);
        ureg[k2l][1] = bc16(qv.y);
        ureg[k2l][2] = bc16(qv.z);
        ureg[k2l][3] = bc16(qv.w);
    }
#pragma unroll
    for (int k2l = REG_K2; k2l < 64; ++k2l)
        ldsu[(size_t)(k2l - REG_K2) * 512 + t] = Uq[(size_t)k2l * 512 + t];

    // ---- state init ----
    float c = 0.f;
    if (s == 0) c = cstate[(size_t)(d * BB + b) * UU + j];
    if (t < 256) hsh[t] = (_Float16)hstate[(size_t)(d * BB + b) * UU + t];
    __syncthreads();

    const _Float16* xzrow = xz16 + (size_t)(d * BB + b) * CT * NZ;
    float* outb = out + (size_t)b * TT * (2 * UU) + d * UU;

    float hn = 0.f;
    for (int tl = 0; tl < CT; ++tl) {
        float x0 = 0.f, x1 = 0.f, x2 = 0.f, x3 = 0.f;
        if (s == 0) {
            const _Float16* p = xzrow + (size_t)tl * NZ + j;
            x0 = (float)p[0]; x1 = (float)p[256];
            x2 = (float)p[512]; x3 = (float)p[768];
        }

        float a0 = 0.f, a1 = 0.f, a2 = 0.f, a3 = 0.f;

        // LDS-resident part first (loads issue early)
#pragma unroll
        for (int k2b = 12; k2b < 16; ++k2b) {
            uint4 hq = hshq[s * 16 + k2b];
            f16x2 hw[4] = {bc16(hq.x), bc16(hq.y), bc16(hq.z), bc16(hq.w)};
#pragma unroll
            for (int r = 0; r < 4; ++r) {
                const int k2l = k2b * 4 + r;
                uint4 uq = ldsu[(size_t)(k2l - REG_K2) * 512 + t];
                f16x2 u0 = bc16(uq.x), u1 = bc16(uq.y), u2 = bc16(uq.z), u3 = bc16(uq.w);
                a0 = __builtin_amdgcn_fdot2(hw[r], u0, a0, false);
                a1 = __builtin_amdgcn_fdot2(hw[r], u1, a1, false);
                a2 = __builtin_amdgcn_fdot2(hw[r], u2, a2, false);
                a3 = __builtin_amdgcn_fdot2(hw[r], u3, a3, false);
            }
        }
        // register-resident part
#pragma unroll
        for (int k2b = 0; k2b < 12; ++k2b) {
            uint4 hq = hshq[s * 16 + k2b];
            f16x2 hw[4] = {bc16(hq.x), bc16(hq.y), bc16(hq.z), bc16(hq.w)};
#pragma unroll
            for (int r = 0; r < 4; ++r) {
                const int k2l = k2b * 4 + r;
                a0 = __builtin_amdgcn_fdot2(hw[r], ureg[k2l][0], a0, false);
                a1 = __builtin_amdgcn_fdot2(hw[r], ureg[k2l][1], a1, false);
                a2 = __builtin_amdgcn_fdot2(hw[r], ureg[k2l][2], a2, false);
                a3 = __builtin_amdgcn_fdot2(hw[r], ureg[k2l][3], a3, false);
            }
        }

        if (s == 1) part[j] = make_float4(a0, a1, a2, a3);
        __syncthreads();

        if (s == 0) {
            float4 pr = part[j];
            float zi = a0 + pr.x + x0;
            float zf = a1 + pr.y + x1;
            float zg = a2 + pr.z + x2;
            float zo = a3 + pr.w + x3;
            float ig = sigm_f(zi), fg = sigm_f(zf), gg = tanh_f(zg), og = sigm_f(zo);
            c = fg * c + ig * gg;
            hn = og * tanh_f(c);
            int tsrc = d ? (TT - 1 - (c0 + tl)) : (c0 + tl);
            outb[(size_t)tsrc * (2 * UU) + j] = hn;
            hsh[j] = (_Float16)hn;
        }
        __syncthreads();
    }

    if (s == 0) {
        hstate[(size_t)(d * BB + b) * UU + j] = hn;
        cstate[(size_t)(d * BB + b) * UU + j] = c;
    }
}

// ---------------------------------------------------------------------------
// Final h/c copy into d_out tail sections
// ---------------------------------------------------------------------------
__global__ __launch_bounds__(256) void enc_final(
    const float* __restrict__ hstate, const float* __restrict__ cstate,
    float* __restrict__ out)
{
    int idx = blockIdx.x * 256 + threadIdx.x;
    if (idx >= 2 * BB * UU) return;
    int d = idx / (BB * UU);
    int rem = idx - d * (BB * UU);
    int b = rem / UU;
    int j = rem - b * UU;
    size_t OUT_H = (size_t)BB * TT * (2 * UU);
    size_t HSZ = (size_t)BB * (2 * UU);
    out[OUT_H + (size_t)b * (2 * UU) + d * UU + j] = hstate[idx];
    out[OUT_H + HSZ + (size_t)b * (2 * UU) + d * UU + j] = cstate[idx];
}

// ---------------------------------------------------------------------------
extern "C" void kernel_launch(void* const* d_in, const int* in_sizes, int n_in,
                              void* d_out, int out_size, void* d_ws, size_t ws_size,
                              hipStream_t stream)
{
    const float* x  = (const float*)d_in[0];
    const float* Wf = (const float*)d_in[1];
    const float* Uf = (const float*)d_in[2];
    const float* bf = (const float*)d_in[3];
    const float* Wb = (const float*)d_in[4];
    const float* Ub = (const float*)d_in[5];
    const float* bb = (const float*)d_in[6];
    float* out = (float*)d_out;

    const size_t x16_bytes   = (size_t)BB * TT * FF * 2;             // 64 MiB
    const size_t wt_bytes    = (size_t)2 * NZ * FF * 2;              // 2 MiB
    const size_t upk_bytes   = (size_t)2 * 64 * 512 * sizeof(uint4); // 1 MiB
    const size_t state_bytes = (size_t)2 * BB * UU * sizeof(float);  // 128 KiB each

    int CT = TT;
    while (CT > 8) {
        size_t need = x16_bytes + wt_bytes + upk_bytes + 2 * state_bytes
                    + (size_t)2 * BB * CT * NZ * 2;
        if (need <= ws_size) break;
        CT >>= 1;
    }

    char* wsb = (char*)d_ws;
    _Float16* x16 = (_Float16*)wsb;
    _Float16* WT  = (_Float16*)(wsb + x16_bytes);
    uint4* Upkr   = (uint4*)(wsb + x16_bytes + wt_bytes);
    float* hstate = (float*)(wsb + x16_bytes + wt_bytes + upk_bytes);
    float* cstate = hstate + 2 * BB * UU;
    _Float16* xz16 = (_Float16*)(wsb + x16_bytes + wt_bytes + upk_bytes + 2 * state_bytes);

    (void)hipFuncSetAttribute(reinterpret_cast<const void*>(enc_lstm_persist),
                              hipFuncAttributeMaxDynamicSharedMemorySize,
                              (int)LSTM_SHBYTES);

    enc_cast_x<<<4096, 256, 0, stream>>>(x, x16, BB * TT * FF / 4);
    enc_cast_wt<<<dim3(8, 16, 2), 256, 0, stream>>>(Wf, Wb, WT);
    enc_pack_u16<<<(2 * 64 * 512 + 255) / 256, 256, 0, stream>>>(Uf, Ub, Upkr);
    enc_zero<<<(2 * 2 * BB * UU + 255) / 256, 256, 0, stream>>>(hstate, 2 * 2 * BB * UU);

    for (int c0 = 0; c0 < TT; c0 += CT) {
        dim3 ggrid((2 * BB * CT) / 128, NZ / 128);
        enc_gemm16<<<ggrid, 256, 0, stream>>>(x16, WT, bf, bb, xz16, c0, CT);
        enc_lstm_persist<<<128, LSTM_THREADS, LSTM_SHBYTES, stream>>>(
            xz16, Upkr, hstate, cstate, out, c0, CT);
    }
    enc_final<<<(2 * BB * UU + 255) / 256, 256, 0, stream>>>(hstate, cstate, out);
}

// Round 5
// 1878.007 us; speedup vs baseline: 5.7466x; 1.0207x over previous
//
#include <hip/hip_runtime.h>
#include <cstdint>
#include <cstddef>

typedef _Float16 f16x2 __attribute__((ext_vector_type(2)));
typedef _Float16 half4 __attribute__((ext_vector_type(4)));
typedef _Float16 half8 __attribute__((ext_vector_type(8)));
typedef float f32x4 __attribute__((ext_vector_type(4)));

static constexpr int BB = 64;    // batch
static constexpr int TT = 1024;  // time steps
static constexpr int FF = 512;   // input features
static constexpr int UU = 256;   // hidden units per direction
static constexpr int NZ = 1024;  // 4*UU gate width

static constexpr size_t LSTM_SHBYTES = 90112;   // force 1 block/CU (160KiB LDS pool)

__device__ __forceinline__ f16x2 bc16(unsigned int v) { return __builtin_bit_cast(f16x2, v); }

__device__ __forceinline__ void st_u32_rlx(unsigned int* p, unsigned int v)
{
    __hip_atomic_store(p, v, __ATOMIC_RELAXED, __HIP_MEMORY_SCOPE_AGENT);
}
__device__ __forceinline__ unsigned int ld_u32_rlx(const unsigned int* p)
{
    return __hip_atomic_load(p, __ATOMIC_RELAXED, __HIP_MEMORY_SCOPE_AGENT);
}

// ---------------------------------------------------------------------------
// Cast x fp32 -> f16 (flat)
// ---------------------------------------------------------------------------
__global__ __launch_bounds__(256) void enc_cast_x(
    const float* __restrict__ x, _Float16* __restrict__ x16, int n4)
{
    int stride = gridDim.x * 256;
    for (int i = blockIdx.x * 256 + threadIdx.x; i < n4; i += stride) {
        float4 v = ((const float4*)x)[i];
        half4 o;
        o.x = (_Float16)v.x; o.y = (_Float16)v.y;
        o.z = (_Float16)v.z; o.w = (_Float16)v.w;
        ((half4*)x16)[i] = o;
    }
}

// ---------------------------------------------------------------------------
// W [512,1024] fp32 -> WT [dir][1024][512] f16 (transposed)
// ---------------------------------------------------------------------------
__global__ __launch_bounds__(256) void enc_cast_wt(
    const float* __restrict__ Wf, const float* __restrict__ Wb,
    _Float16* __restrict__ WT)
{
    __shared__ float tile[64][65];
    const int t = threadIdx.x;
    const int k0 = blockIdx.x * 64;
    const int n0 = blockIdx.y * 64;
    const int d = blockIdx.z;
    const float* W = d ? Wb : Wf;
    _Float16* WTd = WT + (size_t)d * NZ * FF;
#pragma unroll
    for (int p = 0; p < 16; ++p) {
        int idx = p * 256 + t;
        int r = idx >> 6, c = idx & 63;
        tile[r][c] = W[(size_t)(k0 + r) * NZ + n0 + c];
    }
    __syncthreads();
#pragma unroll
    for (int p = 0; p < 16; ++p) {
        int idx = p * 256 + t;
        int r = idx >> 6, c = idx & 63;
        WTd[(size_t)(n0 + r) * FF + k0 + c] = (_Float16)tile[c][r];
    }
}

// ---------------------------------------------------------------------------
// Pack U into per-thread 4-way-k-split layout:
// Upkr2[(d*128 + k2)*256 + j] = uint4 of 4 gate words;
// word g = { U_d[2*k2][g*256+j], U_d[2*k2+1][g*256+j] } as f16x2.
// ---------------------------------------------------------------------------
__global__ __launch_bounds__(256) void enc_pack_u16v2(
    const float* __restrict__ Uf, const float* __restrict__ Ub,
    uint4* __restrict__ Upkr2)
{
    int idx = blockIdx.x * 256 + threadIdx.x;     // 0 .. 65535
    if (idx >= 2 * 128 * 256) return;
    int d  = idx >> 15;
    int k2 = (idx >> 8) & 127;
    int j  = idx & 255;
    int k = 2 * k2;
    const float* Ud = d ? Ub : Uf;
    unsigned int w[4];
#pragma unroll
    for (int g = 0; g < 4; ++g) {
        f16x2 h;
        h.x = (_Float16)Ud[(size_t)k * NZ + g * 256 + j];
        h.y = (_Float16)Ud[(size_t)(k + 1) * NZ + g * 256 + j];
        w[g] = __builtin_bit_cast(unsigned int, h);
    }
    Upkr2[idx] = make_uint4(w[0], w[1], w[2], w[3]);
}

__global__ __launch_bounds__(256) void enc_zero(float* __restrict__ p, int n)
{
    int i = blockIdx.x * 256 + threadIdx.x;
    if (i < n) p[i] = 0.f;
}

// ---------------------------------------------------------------------------
// MFMA GEMM: xz16[r, n] = x16_row(r) . W_d[:, n] + b_d[n]   (unchanged R3)
// ---------------------------------------------------------------------------
__global__ __launch_bounds__(256) void enc_gemm16(
    const _Float16* __restrict__ x16, const _Float16* __restrict__ WT,
    const float* __restrict__ bf, const float* __restrict__ bb,
    _Float16* __restrict__ xz16, int c0, int CT)
{
    __shared__ __align__(16) _Float16 Ash[128][40];
    __shared__ __align__(16) _Float16 Bsh[128][40];

    const int t = threadIdx.x;
    const int r0 = blockIdx.x * 128;
    const int n0 = blockIdx.y * 128;
    const int MperD = BB * CT;
    const int d = r0 / MperD;

    const int srow = t >> 2;
    const int koff = (t & 3) * 8;

    auto xrowptr = [&](int r) -> const _Float16* {
        int rd = r - d * MperD;
        int b = rd / CT;
        int tl = rd - b * CT;
        int tsrc = d ? (TT - 1 - (c0 + tl)) : (c0 + tl);
        return x16 + ((size_t)b * TT + tsrc) * FF;
    };
    const _Float16* ap0 = xrowptr(r0 + srow);
    const _Float16* ap1 = xrowptr(r0 + 64 + srow);
    const _Float16* wp0 = WT + (size_t)(d * NZ + n0 + srow) * FF;
    const _Float16* wp1 = wp0 + (size_t)64 * FF;

    const int lane = t & 63;
    const int w = t >> 6;
    const int wm = w >> 1, wn = w & 1;
    const int l15 = lane & 15;
    const int kq = (lane >> 4) * 8;

    f32x4 acc[4][4];
#pragma unroll
    for (int i = 0; i < 4; ++i)
#pragma unroll
        for (int j = 0; j < 4; ++j) acc[i][j] = (f32x4)0.f;

    for (int ks = 0; ks < FF / 32; ++ks) {
        const int k0 = ks * 32;
        uint4 av0 = *(const uint4*)(ap0 + k0 + koff);
        uint4 av1 = *(const uint4*)(ap1 + k0 + koff);
        uint4 bv0 = *(const uint4*)(wp0 + k0 + koff);
        uint4 bv1 = *(const uint4*)(wp1 + k0 + koff);
        __syncthreads();
        *(uint4*)&Ash[srow][koff]      = av0;
        *(uint4*)&Ash[64 + srow][koff] = av1;
        *(uint4*)&Bsh[srow][koff]      = bv0;
        *(uint4*)&Bsh[64 + srow][koff] = bv1;
        __syncthreads();

        half8 af[4], bfr[4];
#pragma unroll
        for (int mf = 0; mf < 4; ++mf)
            af[mf] = *(const half8*)&Ash[wm * 64 + mf * 16 + l15][kq];
#pragma unroll
        for (int nf = 0; nf < 4; ++nf)
            bfr[nf] = *(const half8*)&Bsh[wn * 64 + nf * 16 + l15][kq];
#pragma unroll
        for (int mf = 0; mf < 4; ++mf)
#pragma unroll
            for (int nf = 0; nf < 4; ++nf)
                acc[mf][nf] = __builtin_amdgcn_mfma_f32_16x16x32_f16(
                    af[mf], bfr[nf], acc[mf][nf], 0, 0, 0);
    }

    const float* bd = d ? bb : bf;
    const int rbase = r0 + wm * 64;
    const int cbase = n0 + wn * 64;
#pragma unroll
    for (int nf = 0; nf < 4; ++nf) {
        const int cc = cbase + nf * 16 + l15;
        const float bia = bd[cc];
#pragma unroll
        for (int mf = 0; mf < 4; ++mf) {
#pragma unroll
            for (int rg = 0; rg < 4; ++rg) {
                int rr = rbase + mf * 16 + (lane >> 4) * 4 + rg;
                xz16[(size_t)rr * NZ + cc] = (_Float16)(acc[mf][nf][rg] + bia);
            }
        }
    }
}

// ---------------------------------------------------------------------------
// Split-chain recurrence: 256 blocks = (chain c 0..127) x (j-half jh 0/1).
// Block holds U[:, its 128 j's] entirely in VGPRs (128 f16x2 words/thread).
// Thread t: s = t>>7 (k-quarter), jl = t&127.
// Per-step h exchange via SELF-VALIDATING TAGGED WORDS in global memory:
//   hbuf[(step&1)][beta][jl] = (step << 16) | f16(h)
// Reader spins until tag == step (exact compare: replay-safe, since a stale
// equal tag implies the bit-identical value from the previous deterministic
// replay). Parity double-buffer makes overwrite-before-read impossible:
// A stores step s+2 only after A read B's s+1, which required B to have
// read A's s.
// Grid = 256 blocks x 90KiB LDS -> 1 block/CU -> all co-resident.
// ---------------------------------------------------------------------------
__device__ __forceinline__ float sigm_f(float xv)
{
    return 1.0f / (1.0f + __expf(-xv));
}
__device__ __forceinline__ float tanh_f(float xv)
{
    return 2.0f / (1.0f + __expf(-2.0f * xv)) - 1.0f;
}

__global__ __launch_bounds__(512, 2) void enc_lstm_split(
    const _Float16* __restrict__ xz16, const uint4* __restrict__ Upkr2,
    float* __restrict__ hstate, float* __restrict__ cstate,
    unsigned int* __restrict__ hbuf,
    float* __restrict__ out, int c0, int CT)
{
    extern __shared__ char smem2[];
    float4*    parts = (float4*)smem2;                 // 3*128*16 = 6144 B
    _Float16*  hsh   = (_Float16*)(smem2 + 6144);      // 512 B
    uint4*     hshq  = (uint4*)hsh;

    const int t  = threadIdx.x;
    const int s  = t >> 7;          // k-quarter 0..3
    const int jl = t & 127;
    const int beta = blockIdx.x;
    const int jh = (beta >> 3) & 1;
    const int c  = ((beta >> 4) << 3) | (beta & 7);    // chain 0..127
    const int d  = c >> 6;
    const int b  = c & 63;
    const int j  = jh * 128 + jl;
    const int partner = beta ^ 8;

    // ---- persistent U: 32 k2-pairs x 4 gates, all in VGPRs ----
    const uint4* Uq = Upkr2 + ((size_t)d * 128 + s * 32) * 256 + j;
    f16x2 ureg[32][4];
#pragma unroll
    for (int m = 0; m < 32; ++m) {
        uint4 qv = Uq[(size_t)m * 256];
        ureg[m][0] = bc16(qv.x);
        ureg[m][1] = bc16(qv.y);
        ureg[m][2] = bc16(qv.z);
        ureg[m][3] = bc16(qv.w);
    }

    // ---- state init ----
    float cr = 0.f, hn = 0.f;
    if (s == 0) cr = cstate[(size_t)c * UU + j];
    if (t < 256) hsh[t] = (_Float16)hstate[(size_t)c * UU + t];
    __syncthreads();

    const _Float16* xzrow = xz16 + (size_t)c * CT * NZ;
    float* outb = out + (size_t)b * TT * (2 * UU) + d * UU;

    for (int tl = 0; tl < CT; ++tl) {
        const int step = c0 + tl + 1;

        float x0 = 0.f, x1 = 0.f, x2 = 0.f, x3 = 0.f;
        if (s == 0) {
            const _Float16* p = xzrow + (size_t)tl * NZ + j;
            x0 = (float)p[0];   x1 = (float)p[256];
            x2 = (float)p[512]; x3 = (float)p[768];
        }

        float a0 = 0.f, a1 = 0.f, a2 = 0.f, a3 = 0.f;
#pragma unroll
        for (int r = 0; r < 8; ++r) {
            uint4 hq = hshq[s * 8 + r];            // broadcast read
            f16x2 hw[4] = {bc16(hq.x), bc16(hq.y), bc16(hq.z), bc16(hq.w)};
#pragma unroll
            for (int q = 0; q < 4; ++q) {
                const int m = r * 4 + q;
                a0 = __builtin_amdgcn_fdot2(hw[q], ureg[m][0], a0, false);
                a1 = __builtin_amdgcn_fdot2(hw[q], ureg[m][1], a1, false);
                a2 = __builtin_amdgcn_fdot2(hw[q], ureg[m][2], a2, false);
                a3 = __builtin_amdgcn_fdot2(hw[q], ureg[m][3], a3, false);
            }
        }

        if (s) parts[(s - 1) * 128 + jl] = make_float4(a0, a1, a2, a3);
        __syncthreads();                           // bar1: parts ready

        if (s == 0) {
            float4 p1 = parts[jl], p2 = parts[128 + jl], p3 = parts[256 + jl];
            float zi = a0 + p1.x + p2.x + p3.x + x0;
            float zf = a1 + p1.y + p2.y + p3.y + x1;
            float zg = a2 + p1.z + p2.z + p3.z + x2;
            float zo = a3 + p1.w + p2.w + p3.w + x3;
            float ig = sigm_f(zi), fg = sigm_f(zf), gg = tanh_f(zg), og = sigm_f(zo);
            cr = fg * cr + ig * gg;
            hn = og * tanh_f(cr);
            _Float16 h16 = (_Float16)hn;
            // tagged publish first (partner is waiting on it)
            st_u32_rlx(&hbuf[((size_t)(step & 1) * 256 + beta) * 128 + jl],
                       ((unsigned int)step << 16)
                       | (unsigned int)__builtin_bit_cast(unsigned short, h16));
            hsh[j] = h16;
            int tsrc = d ? (TT - 1 - (c0 + tl)) : (c0 + tl);
            outb[(size_t)tsrc * (2 * UU) + j] = hn;
        }
        if (s == 1) {
            const unsigned int* p =
                &hbuf[((size_t)(step & 1) * 256 + partner) * 128 + jl];
            unsigned int v;
            do {
                v = ld_u32_rlx(p);
            } while ((v >> 16) != (unsigned int)step);
            hsh[(1 - jh) * 128 + jl] =
                __builtin_bit_cast(_Float16, (unsigned short)(v & 0xffffu));
        }
        __syncthreads();                           // bar2: full hsh valid
    }

    if (s == 0) {
        hstate[(size_t)c * UU + j] = hn;
        cstate[(size_t)c * UU + j] = cr;
    }
}

// ---------------------------------------------------------------------------
// Final h/c copy into d_out tail sections
// ---------------------------------------------------------------------------
__global__ __launch_bounds__(256) void enc_final(
    const float* __restrict__ hstate, const float* __restrict__ cstate,
    float* __restrict__ out)
{
    int idx = blockIdx.x * 256 + threadIdx.x;
    if (idx >= 2 * BB * UU) return;
    int d = idx / (BB * UU);
    int rem = idx - d * (BB * UU);
    int b = rem / UU;
    int j = rem - b * UU;
    size_t OUT_H = (size_t)BB * TT * (2 * UU);
    size_t HSZ = (size_t)BB * (2 * UU);
    out[OUT_H + (size_t)b * (2 * UU) + d * UU + j] = hstate[idx];
    out[OUT_H + HSZ + (size_t)b * (2 * UU) + d * UU + j] = cstate[idx];
}

// ---------------------------------------------------------------------------
extern "C" void kernel_launch(void* const* d_in, const int* in_sizes, int n_in,
                              void* d_out, int out_size, void* d_ws, size_t ws_size,
                              hipStream_t stream)
{
    const float* x  = (const float*)d_in[0];
    const float* Wf = (const float*)d_in[1];
    const float* Uf = (const float*)d_in[2];
    const float* bf = (const float*)d_in[3];
    const float* Wb = (const float*)d_in[4];
    const float* Ub = (const float*)d_in[5];
    const float* bb = (const float*)d_in[6];
    float* out = (float*)d_out;

    const size_t x16_bytes   = (size_t)BB * TT * FF * 2;             // 64 MiB
    const size_t wt_bytes    = (size_t)2 * NZ * FF * 2;              // 2 MiB
    const size_t upk_bytes   = (size_t)2 * 128 * 256 * sizeof(uint4);// 1 MiB
    const size_t state_bytes = (size_t)2 * BB * UU * sizeof(float);  // 128 KiB each
    const size_t hbuf_bytes  = (size_t)2 * 256 * 128 * 4;            // 256 KiB
    const size_t fixed = x16_bytes + wt_bytes + upk_bytes + 2 * state_bytes
                       + hbuf_bytes;

    int CT = TT;
    while (CT > 8) {
        size_t need = fixed + (size_t)2 * BB * CT * NZ * 2;
        if (need <= ws_size) break;
        CT >>= 1;
    }

    char* wsb = (char*)d_ws;
    _Float16* x16 = (_Float16*)wsb;
    _Float16* WT  = (_Float16*)(wsb + x16_bytes);
    uint4* Upkr2  = (uint4*)(wsb + x16_bytes + wt_bytes);
    float* hstate = (float*)(wsb + x16_bytes + wt_bytes + upk_bytes);
    float* cstate = hstate + 2 * BB * UU;
    unsigned int* hbuf = (unsigned int*)(wsb + x16_bytes + wt_bytes + upk_bytes
                                         + 2 * state_bytes);
    _Float16* xz16 = (_Float16*)(wsb + fixed);

    (void)hipFuncSetAttribute(reinterpret_cast<const void*>(enc_lstm_split),
                              hipFuncAttributeMaxDynamicSharedMemorySize,
                              (int)LSTM_SHBYTES);

    enc_cast_x<<<4096, 256, 0, stream>>>(x, x16, BB * TT * FF / 4);
    enc_cast_wt<<<dim3(8, 16, 2), 256, 0, stream>>>(Wf, Wb, WT);
    enc_pack_u16v2<<<(2 * 128 * 256 + 255) / 256, 256, 0, stream>>>(Uf, Ub, Upkr2);
    enc_zero<<<(2 * 2 * BB * UU + 255) / 256, 256, 0, stream>>>(hstate, 2 * 2 * BB * UU);

    for (int c0 = 0; c0 < TT; c0 += CT) {
        dim3 ggrid((2 * BB * CT) / 128, NZ / 128);
        enc_gemm16<<<ggrid, 256, 0, stream>>>(x16, WT, bf, bb, xz16, c0, CT);
        enc_lstm_split<<<256, 512, LSTM_SHBYTES, stream>>>(
            xz16, Upkr2, hstate, cstate, hbuf, out, c0, CT);
    }
    enc_final<<<(2 * BB * UU + 255) / 256, 256, 0, stream>>>(hstate, cstate, out);
}

// Round 7
// 1697.210 us; speedup vs baseline: 6.3587x; 1.1065x over previous
//
#include <hip/hip_runtime.h>
#include <cstdint>
#include <cstddef>

typedef _Float16 f16x2 __attribute__((ext_vector_type(2)));
typedef _Float16 half4 __attribute__((ext_vector_type(4)));
typedef _Float16 half8 __attribute__((ext_vector_type(8)));
typedef float f32x4 __attribute__((ext_vector_type(4)));

static constexpr int BB = 64;    // batch
static constexpr int TT = 1024;  // time steps
static constexpr int FF = 512;   // input features
static constexpr int UU = 256;   // hidden units per direction
static constexpr int NZ = 1024;  // 4*UU gate width

static constexpr size_t LSTM_SHBYTES = 90112;   // force 1 block/CU (160KiB LDS pool)

__device__ __forceinline__ f16x2 bc16(unsigned int v) { return __builtin_bit_cast(f16x2, v); }

__device__ __forceinline__ void st_u32_rlx(unsigned int* p, unsigned int v)
{
    __hip_atomic_store(p, v, __ATOMIC_RELAXED, __HIP_MEMORY_SCOPE_AGENT);
}
__device__ __forceinline__ unsigned int ld_u32_rlx(const unsigned int* p)
{
    return __hip_atomic_load(p, __ATOMIC_RELAXED, __HIP_MEMORY_SCOPE_AGENT);
}

// Raw barrier: drains LDS ops only; leaves global loads (vmcnt) in flight so
// cross-step prefetches survive. (HIP __syncthreads drains vmcnt(0) too.)
__device__ __forceinline__ void bar_lgkm()
{
    asm volatile("s_waitcnt lgkmcnt(0)\n\ts_barrier" ::: "memory");
}

// ---------------------------------------------------------------------------
// Cast x fp32 -> f16 (flat)
// ---------------------------------------------------------------------------
__global__ __launch_bounds__(256) void enc_cast_x(
    const float* __restrict__ x, _Float16* __restrict__ x16, int n4)
{
    int stride = gridDim.x * 256;
    for (int i = blockIdx.x * 256 + threadIdx.x; i < n4; i += stride) {
        float4 v = ((const float4*)x)[i];
        half4 o;
        o.x = (_Float16)v.x; o.y = (_Float16)v.y;
        o.z = (_Float16)v.z; o.w = (_Float16)v.w;
        ((half4*)x16)[i] = o;
    }
}

// ---------------------------------------------------------------------------
// W [512,1024] fp32 -> WT [dir][1024][512] f16 (transposed)
// ---------------------------------------------------------------------------
__global__ __launch_bounds__(256) void enc_cast_wt(
    const float* __restrict__ Wf, const float* __restrict__ Wb,
    _Float16* __restrict__ WT)
{
    __shared__ float tile[64][65];
    const int t = threadIdx.x;
    const int k0 = blockIdx.x * 64;
    const int n0 = blockIdx.y * 64;
    const int d = blockIdx.z;
    const float* W = d ? Wb : Wf;
    _Float16* WTd = WT + (size_t)d * NZ * FF;
#pragma unroll
    for (int p = 0; p < 16; ++p) {
        int idx = p * 256 + t;
        int r = idx >> 6, c = idx & 63;
        tile[r][c] = W[(size_t)(k0 + r) * NZ + n0 + c];
    }
    __syncthreads();
#pragma unroll
    for (int p = 0; p < 16; ++p) {
        int idx = p * 256 + t;
        int r = idx >> 6, c = idx & 63;
        WTd[(size_t)(n0 + r) * FF + k0 + c] = (_Float16)tile[c][r];
    }
}

// ---------------------------------------------------------------------------
// Pack U into per-thread 4-way-k-split layout:
// Upkr2[(d*128 + k2)*256 + j] = uint4 of 4 gate words;
// word g = { U_d[2*k2][g*256+j], U_d[2*k2+1][g*256+j] } as f16x2.
// ---------------------------------------------------------------------------
__global__ __launch_bounds__(256) void enc_pack_u16v2(
    const float* __restrict__ Uf, const float* __restrict__ Ub,
    uint4* __restrict__ Upkr2)
{
    int idx = blockIdx.x * 256 + threadIdx.x;     // 0 .. 65535
    if (idx >= 2 * 128 * 256) return;
    int d  = idx >> 15;
    int k2 = (idx >> 8) & 127;
    int j  = idx & 255;
    int k = 2 * k2;
    const float* Ud = d ? Ub : Uf;
    unsigned int w[4];
#pragma unroll
    for (int g = 0; g < 4; ++g) {
        f16x2 h;
        h.x = (_Float16)Ud[(size_t)k * NZ + g * 256 + j];
        h.y = (_Float16)Ud[(size_t)(k + 1) * NZ + g * 256 + j];
        w[g] = __builtin_bit_cast(unsigned int, h);
    }
    Upkr2[idx] = make_uint4(w[0], w[1], w[2], w[3]);
}

__global__ __launch_bounds__(256) void enc_zero(float* __restrict__ p, int n)
{
    int i = blockIdx.x * 256 + threadIdx.x;
    if (i < n) p[i] = 0.f;
}

// ---------------------------------------------------------------------------
// MFMA GEMM: xz16[r, n] = x16_row(r) . W_d[:, n] + b_d[n]   (unchanged)
// ---------------------------------------------------------------------------
__global__ __launch_bounds__(256) void enc_gemm16(
    const _Float16* __restrict__ x16, const _Float16* __restrict__ WT,
    const float* __restrict__ bf, const float* __restrict__ bb,
    _Float16* __restrict__ xz16, int c0, int CT)
{
    __shared__ __align__(16) _Float16 Ash[128][40];
    __shared__ __align__(16) _Float16 Bsh[128][40];

    const int t = threadIdx.x;
    const int r0 = blockIdx.x * 128;
    const int n0 = blockIdx.y * 128;
    const int MperD = BB * CT;
    const int d = r0 / MperD;

    const int srow = t >> 2;
    const int koff = (t & 3) * 8;

    auto xrowptr = [&](int r) -> const _Float16* {
        int rd = r - d * MperD;
        int b = rd / CT;
        int tl = rd - b * CT;
        int tsrc = d ? (TT - 1 - (c0 + tl)) : (c0 + tl);
        return x16 + ((size_t)b * TT + tsrc) * FF;
    };
    const _Float16* ap0 = xrowptr(r0 + srow);
    const _Float16* ap1 = xrowptr(r0 + 64 + srow);
    const _Float16* wp0 = WT + (size_t)(d * NZ + n0 + srow) * FF;
    const _Float16* wp1 = wp0 + (size_t)64 * FF;

    const int lane = t & 63;
    const int w = t >> 6;
    const int wm = w >> 1, wn = w & 1;
    const int l15 = lane & 15;
    const int kq = (lane >> 4) * 8;

    f32x4 acc[4][4];
#pragma unroll
    for (int i = 0; i < 4; ++i)
#pragma unroll
        for (int j = 0; j < 4; ++j) acc[i][j] = (f32x4)0.f;

    for (int ks = 0; ks < FF / 32; ++ks) {
        const int k0 = ks * 32;
        uint4 av0 = *(const uint4*)(ap0 + k0 + koff);
        uint4 av1 = *(const uint4*)(ap1 + k0 + koff);
        uint4 bv0 = *(const uint4*)(wp0 + k0 + koff);
        uint4 bv1 = *(const uint4*)(wp1 + k0 + koff);
        __syncthreads();
        *(uint4*)&Ash[srow][koff]      = av0;
        *(uint4*)&Ash[64 + srow][koff] = av1;
        *(uint4*)&Bsh[srow][koff]      = bv0;
        *(uint4*)&Bsh[64 + srow][koff] = bv1;
        __syncthreads();

        half8 af[4], bfr[4];
#pragma unroll
        for (int mf = 0; mf < 4; ++mf)
            af[mf] = *(const half8*)&Ash[wm * 64 + mf * 16 + l15][kq];
#pragma unroll
        for (int nf = 0; nf < 4; ++nf)
            bfr[nf] = *(const half8*)&Bsh[wn * 64 + nf * 16 + l15][kq];
#pragma unroll
        for (int mf = 0; mf < 4; ++mf)
#pragma unroll
            for (int nf = 0; nf < 4; ++nf)
                acc[mf][nf] = __builtin_amdgcn_mfma_f32_16x16x32_f16(
                    af[mf], bfr[nf], acc[mf][nf], 0, 0, 0);
    }

    const float* bd = d ? bb : bf;
    const int rbase = r0 + wm * 64;
    const int cbase = n0 + wn * 64;
#pragma unroll
    for (int nf = 0; nf < 4; ++nf) {
        const int cc = cbase + nf * 16 + l15;
        const float bia = bd[cc];
#pragma unroll
        for (int mf = 0; mf < 4; ++mf) {
#pragma unroll
            for (int rg = 0; rg < 4; ++rg) {
                int rr = rbase + mf * 16 + (lane >> 4) * 4 + rg;
                xz16[(size_t)rr * NZ + cc] = (_Float16)(acc[mf][nf][rg] + bia);
            }
        }
    }
}

// ---------------------------------------------------------------------------
// Split-chain recurrence v3: 256 blocks = (chain c 0..127) x (j-half jh 0/1).
// U (j-half) fully register-resident. s-group (128 thr) = k-quarter.
// own  = s-groups whose k-range is this block's own h-half (locally produced).
// isx  = one partner-consuming, NON-publisher s-group: finalizes the exchange.
//
// Iteration tl consumes h_{c0+tl} and produces h_{c0+tl+1}:
//   ph1: own dots (need no partner data) || isx: spin for tag c0+tl (tl>0)
//   bar1 (lgkm only)
//   ph2: partner-half dots
//   bar2
//   ph3: s==0 reduce+gates+publish(tag step)+own hsh+out + xz prefetch
//        isx: sample next tag's word (prefetch)
//   bar3
// Wait is strictly for the PREVIOUS step's publish -> deadlock-free by
// induction (tl=0 needs no exchange: both halves loaded from hstate).
// Parity slot (tag&1): publish of tag T overwrites T-2, provably consumed.
// Raw lgkm-barriers keep the prefetch loads in flight across phases.
// ---------------------------------------------------------------------------
__device__ __forceinline__ float sigm_f(float xv)
{
    return 1.0f / (1.0f + __expf(-xv));
}
__device__ __forceinline__ float tanh_f(float xv)
{
    return 2.0f / (1.0f + __expf(-2.0f * xv)) - 1.0f;
}

__global__ __launch_bounds__(512, 2) void enc_lstm_split(
    const _Float16* __restrict__ xz16, const uint4* __restrict__ Upkr2,
    float* __restrict__ hstate, float* __restrict__ cstate,
    unsigned int* __restrict__ hbuf,
    float* __restrict__ out, int c0, int CT)
{
    extern __shared__ char smem2[];
    float4*    parts = (float4*)smem2;                 // 4*128*16 = 8192 B
    _Float16*  hsh   = (_Float16*)(smem2 + 8192);      // 512 B
    uint4*     hshq  = (uint4*)hsh;

    const int t  = threadIdx.x;
    const int s  = t >> 7;          // k-quarter 0..3
    const int jl = t & 127;
    const int beta = blockIdx.x;
    const int jh = (beta >> 3) & 1;
    const int c  = ((beta >> 4) << 3) | (beta & 7);    // chain 0..127
    const int d  = c >> 6;
    const int b  = c & 63;
    const int j  = jh * 128 + jl;
    const int partner = beta ^ 8;
    const bool own = ((s >> 1) == jh);    // k-range uses own h-half
    const bool isx = (s == (jh ? 1 : 2)); // exchange group (partner-consuming, non-publisher)

    // ---- persistent U: 32 k2-pairs x 4 gates, register-resident ----
    const uint4* Uq = Upkr2 + ((size_t)d * 128 + s * 32) * 256 + j;
    f16x2 ureg[32][4];
#pragma unroll
    for (int m = 0; m < 32; ++m) {
        uint4 qv = Uq[(size_t)m * 256];
        ureg[m][0] = bc16(qv.x);
        ureg[m][1] = bc16(qv.y);
        ureg[m][2] = bc16(qv.z);
        ureg[m][3] = bc16(qv.w);
    }

    // ---- state init ----
    float cr = 0.f, hn = 0.f;
    if (s == 0) cr = cstate[(size_t)c * UU + j];
    if (t < 256) hsh[t] = (_Float16)hstate[(size_t)c * UU + t];
    __syncthreads();

    const _Float16* xzrow = xz16 + (size_t)c * CT * NZ;
    float* outb = out + (size_t)b * TT * (2 * UU) + d * UU;

    // ---- pre-loop prefetches ----
    unsigned short xp0 = 0, xp1 = 0, xp2 = 0, xp3 = 0;
    if (s == 0) {
        const unsigned short* p = (const unsigned short*)xzrow + j;
        xp0 = p[0]; xp1 = p[256]; xp2 = p[512]; xp3 = p[768];
    }
    unsigned int pref = 0;   // tag 0 never matches a real htag

    auto dot4 = [&](float& a0, float& a1, float& a2, float& a3) {
#pragma unroll
        for (int r = 0; r < 8; ++r) {
            uint4 hq = hshq[s * 8 + r];            // broadcast read
            f16x2 hw[4] = {bc16(hq.x), bc16(hq.y), bc16(hq.z), bc16(hq.w)};
#pragma unroll
            for (int q = 0; q < 4; ++q) {
                const int m = r * 4 + q;
                a0 = __builtin_amdgcn_fdot2(hw[q], ureg[m][0], a0, false);
                a1 = __builtin_amdgcn_fdot2(hw[q], ureg[m][1], a1, false);
                a2 = __builtin_amdgcn_fdot2(hw[q], ureg[m][2], a2, false);
                a3 = __builtin_amdgcn_fdot2(hw[q], ureg[m][3], a3, false);
            }
        }
    };

    for (int tl = 0; tl < CT; ++tl) {
        const int step = c0 + tl + 1;   // h produced this iteration
        const int htag = c0 + tl;       // partner h consumed this iteration

        // ---- phase 1: own-half dots || exchange finalize ----
        if (own) {
            float a0 = 0.f, a1 = 0.f, a2 = 0.f, a3 = 0.f;
            dot4(a0, a1, a2, a3);
            parts[s * 128 + jl] = make_float4(a0, a1, a2, a3);
        }
        if (isx && tl > 0) {
            const unsigned int* pp =
                &hbuf[((size_t)(htag & 1) * 256 + partner) * 128 + jl];
            unsigned int v = pref;
            while ((v >> 16) != (unsigned int)htag) {
                __builtin_amdgcn_s_sleep(1);
                v = ld_u32_rlx(pp);
            }
            hsh[(1 - jh) * 128 + jl] =
                __builtin_bit_cast(_Float16, (unsigned short)(v & 0xffffu));
        }
        bar_lgkm();                                // bar1: partner h in hsh

        // ---- phase 2: partner-half dots ----
        if (!own) {
            float a0 = 0.f, a1 = 0.f, a2 = 0.f, a3 = 0.f;
            dot4(a0, a1, a2, a3);
            parts[s * 128 + jl] = make_float4(a0, a1, a2, a3);
        }
        bar_lgkm();                                // bar2: all partials ready

        // ---- phase 3: gates + publish (s==0) ; prefetch sample (isx) ----
        if (s == 0) {
            float4 p0 = parts[jl], p1 = parts[128 + jl];
            float4 p2 = parts[256 + jl], p3 = parts[384 + jl];
            float zi = p0.x + p1.x + p2.x + p3.x
                     + (float)__builtin_bit_cast(_Float16, xp0);
            float zf = p0.y + p1.y + p2.y + p3.y
                     + (float)__builtin_bit_cast(_Float16, xp1);
            float zg = p0.z + p1.z + p2.z + p3.z
                     + (float)__builtin_bit_cast(_Float16, xp2);
            float zo = p0.w + p1.w + p2.w + p3.w
                     + (float)__builtin_bit_cast(_Float16, xp3);
            float ig = sigm_f(zi), fg = sigm_f(zf), gg = tanh_f(zg), og = sigm_f(zo);
            cr = fg * cr + ig * gg;
            hn = og * tanh_f(cr);
            _Float16 h16 = (_Float16)hn;
            // tagged publish first (partner consumes it next iteration)
            st_u32_rlx(&hbuf[((size_t)(step & 1) * 256 + beta) * 128 + jl],
                       ((unsigned int)step << 16)
                       | (unsigned int)__builtin_bit_cast(unsigned short, h16));
            hsh[j] = h16;
            int tsrc = d ? (TT - 1 - (c0 + tl)) : (c0 + tl);
            outb[(size_t)tsrc * (2 * UU) + j] = hn;
            // prefetch next step's xz (stays in flight across raw barriers)
            int tn = (tl + 1 < CT) ? tl + 1 : tl;
            const unsigned short* pn =
                (const unsigned short*)(xzrow + (size_t)tn * NZ) + j;
            xp0 = pn[0]; xp1 = pn[256]; xp2 = pn[512]; xp3 = pn[768];
        }
        if (isx) {
            // sample the word for next iteration's htag (= step)
            pref = ld_u32_rlx(&hbuf[((size_t)(step & 1) * 256 + partner) * 128 + jl]);
        }
        bar_lgkm();                                // bar3: own hsh half updated
    }

    if (s == 0) {
        hstate[(size_t)c * UU + j] = hn;
        cstate[(size_t)c * UU + j] = cr;
    }
}

// ---------------------------------------------------------------------------
// Final h/c copy into d_out tail sections
// ---------------------------------------------------------------------------
__global__ __launch_bounds__(256) void enc_final(
    const float* __restrict__ hstate, const float* __restrict__ cstate,
    float* __restrict__ out)
{
    int idx = blockIdx.x * 256 + threadIdx.x;
    if (idx >= 2 * BB * UU) return;
    int d = idx / (BB * UU);
    int rem = idx - d * (BB * UU);
    int b = rem / UU;
    int j = rem - b * UU;
    size_t OUT_H = (size_t)BB * TT * (2 * UU);
    size_t HSZ = (size_t)BB * (2 * UU);
    out[OUT_H + (size_t)b * (2 * UU) + d * UU + j] = hstate[idx];
    out[OUT_H + HSZ + (size_t)b * (2 * UU) + d * UU + j] = cstate[idx];
}

// ---------------------------------------------------------------------------
extern "C" void kernel_launch(void* const* d_in, const int* in_sizes, int n_in,
                              void* d_out, int out_size, void* d_ws, size_t ws_size,
                              hipStream_t stream)
{
    const float* x  = (const float*)d_in[0];
    const float* Wf = (const float*)d_in[1];
    const float* Uf = (const float*)d_in[2];
    const float* bf = (const float*)d_in[3];
    const float* Wb = (const float*)d_in[4];
    const float* Ub = (const float*)d_in[5];
    const float* bb = (const float*)d_in[6];
    float* out = (float*)d_out;

    const size_t x16_bytes   = (size_t)BB * TT * FF * 2;             // 64 MiB
    const size_t wt_bytes    = (size_t)2 * NZ * FF * 2;              // 2 MiB
    const size_t upk_bytes   = (size_t)2 * 128 * 256 * sizeof(uint4);// 1 MiB
    const size_t state_bytes = (size_t)2 * BB * UU * sizeof(float);  // 128 KiB each
    const size_t hbuf_bytes  = (size_t)2 * 256 * 128 * 4;            // 256 KiB
    const size_t fixed = x16_bytes + wt_bytes + upk_bytes + 2 * state_bytes
                       + hbuf_bytes;

    int CT = TT;
    while (CT > 8) {
        size_t need = fixed + (size_t)2 * BB * CT * NZ * 2;
        if (need <= ws_size) break;
        CT >>= 1;
    }

    char* wsb = (char*)d_ws;
    _Float16* x16 = (_Float16*)wsb;
    _Float16* WT  = (_Float16*)(wsb + x16_bytes);
    uint4* Upkr2  = (uint4*)(wsb + x16_bytes + wt_bytes);
    float* hstate = (float*)(wsb + x16_bytes + wt_bytes + upk_bytes);
    float* cstate = hstate + 2 * BB * UU;
    unsigned int* hbuf = (unsigned int*)(wsb + x16_bytes + wt_bytes + upk_bytes
                                         + 2 * state_bytes);
    _Float16* xz16 = (_Float16*)(wsb + fixed);

    (void)hipFuncSetAttribute(reinterpret_cast<const void*>(enc_lstm_split),
                              hipFuncAttributeMaxDynamicSharedMemorySize,
                              (int)LSTM_SHBYTES);

    enc_cast_x<<<4096, 256, 0, stream>>>(x, x16, BB * TT * FF / 4);
    enc_cast_wt<<<dim3(8, 16, 2), 256, 0, stream>>>(Wf, Wb, WT);
    enc_pack_u16v2<<<(2 * 128 * 256 + 255) / 256, 256, 0, stream>>>(Uf, Ub, Upkr2);
    enc_zero<<<(2 * 2 * BB * UU + 255) / 256, 256, 0, stream>>>(hstate, 2 * 2 * BB * UU);

    for (int c0 = 0; c0 < TT; c0 += CT) {
        dim3 ggrid((2 * BB * CT) / 128, NZ / 128);
        enc_gemm16<<<ggrid, 256, 0, stream>>>(x16, WT, bf, bb, xz16, c0, CT);
        enc_lstm_split<<<256, 512, LSTM_SHBYTES, stream>>>(
            xz16, Upkr2, hstate, cstate, hbuf, out, c0, CT);
    }
    enc_final<<<(2 * BB * UU + 255) / 256, 256, 0, stream>>>(hstate, cstate, out);
}

// Round 8
// 1692.233 us; speedup vs baseline: 6.3774x; 1.0029x over previous
//
#include <hip/hip_runtime.h>
#include <cstdint>
#include <cstddef>

typedef _Float16 f16x2 __attribute__((ext_vector_type(2)));
typedef _Float16 half4 __attribute__((ext_vector_type(4)));
typedef _Float16 half8 __attribute__((ext_vector_type(8)));
typedef float f32x4 __attribute__((ext_vector_type(4)));

static constexpr int BB = 64;    // batch
static constexpr int TT = 1024;  // time steps
static constexpr int FF = 512;   // input features
static constexpr int UU = 256;   // hidden units per direction
static constexpr int NZ = 1024;  // 4*UU gate width

static constexpr size_t LSTM_SHBYTES = 90112;   // force 1 block/CU (160KiB LDS pool)

__device__ __forceinline__ f16x2 bc16(unsigned int v) { return __builtin_bit_cast(f16x2, v); }

__device__ __forceinline__ void st_u32_rlx(unsigned int* p, unsigned int v)
{
    __hip_atomic_store(p, v, __ATOMIC_RELAXED, __HIP_MEMORY_SCOPE_AGENT);
}
__device__ __forceinline__ unsigned int ld_u32_rlx(const unsigned int* p)
{
    return __hip_atomic_load(p, __ATOMIC_RELAXED, __HIP_MEMORY_SCOPE_AGENT);
}

// Raw barrier: drains LDS ops only; leaves global loads (vmcnt) in flight so
// cross-step prefetches survive. (HIP __syncthreads drains vmcnt(0) too.)
__device__ __forceinline__ void bar_lgkm()
{
    asm volatile("s_waitcnt lgkmcnt(0)\n\ts_barrier" ::: "memory");
}

// ---------------------------------------------------------------------------
// Cast x fp32 -> f16 (flat)
// ---------------------------------------------------------------------------
__global__ __launch_bounds__(256) void enc_cast_x(
    const float* __restrict__ x, _Float16* __restrict__ x16, int n4)
{
    int stride = gridDim.x * 256;
    for (int i = blockIdx.x * 256 + threadIdx.x; i < n4; i += stride) {
        float4 v = ((const float4*)x)[i];
        half4 o;
        o.x = (_Float16)v.x; o.y = (_Float16)v.y;
        o.z = (_Float16)v.z; o.w = (_Float16)v.w;
        ((half4*)x16)[i] = o;
    }
}

// ---------------------------------------------------------------------------
// W [512,1024] fp32 -> WT [dir][1024][512] f16 (transposed)
// ---------------------------------------------------------------------------
__global__ __launch_bounds__(256) void enc_cast_wt(
    const float* __restrict__ Wf, const float* __restrict__ Wb,
    _Float16* __restrict__ WT)
{
    __shared__ float tile[64][65];
    const int t = threadIdx.x;
    const int k0 = blockIdx.x * 64;
    const int n0 = blockIdx.y * 64;
    const int d = blockIdx.z;
    const float* W = d ? Wb : Wf;
    _Float16* WTd = WT + (size_t)d * NZ * FF;
#pragma unroll
    for (int p = 0; p < 16; ++p) {
        int idx = p * 256 + t;
        int r = idx >> 6, c = idx & 63;
        tile[r][c] = W[(size_t)(k0 + r) * NZ + n0 + c];
    }
    __syncthreads();
#pragma unroll
    for (int p = 0; p < 16; ++p) {
        int idx = p * 256 + t;
        int r = idx >> 6, c = idx & 63;
        WTd[(size_t)(n0 + r) * FF + k0 + c] = (_Float16)tile[c][r];
    }
}

// ---------------------------------------------------------------------------
// Pack U into per-thread 4-way-k-split layout:
// Upkr2[(d*128 + k2)*256 + j] = uint4 of 4 gate words;
// word g = { U_d[2*k2][g*256+j], U_d[2*k2+1][g*256+j] } as f16x2.
// ---------------------------------------------------------------------------
__global__ __launch_bounds__(256) void enc_pack_u16v2(
    const float* __restrict__ Uf, const float* __restrict__ Ub,
    uint4* __restrict__ Upkr2)
{
    int idx = blockIdx.x * 256 + threadIdx.x;     // 0 .. 65535
    if (idx >= 2 * 128 * 256) return;
    int d  = idx >> 15;
    int k2 = (idx >> 8) & 127;
    int j  = idx & 255;
    int k = 2 * k2;
    const float* Ud = d ? Ub : Uf;
    unsigned int w[4];
#pragma unroll
    for (int g = 0; g < 4; ++g) {
        f16x2 h;
        h.x = (_Float16)Ud[(size_t)k * NZ + g * 256 + j];
        h.y = (_Float16)Ud[(size_t)(k + 1) * NZ + g * 256 + j];
        w[g] = __builtin_bit_cast(unsigned int, h);
    }
    Upkr2[idx] = make_uint4(w[0], w[1], w[2], w[3]);
}

__global__ __launch_bounds__(256) void enc_zero(float* __restrict__ p, int n)
{
    int i = blockIdx.x * 256 + threadIdx.x;
    if (i < n) p[i] = 0.f;
}

// ---------------------------------------------------------------------------
// MFMA GEMM: xz16[r, n] = x16_row(r) . W_d[:, n] + b_d[n]   (unchanged)
// ---------------------------------------------------------------------------
__global__ __launch_bounds__(256) void enc_gemm16(
    const _Float16* __restrict__ x16, const _Float16* __restrict__ WT,
    const float* __restrict__ bf, const float* __restrict__ bb,
    _Float16* __restrict__ xz16, int c0, int CT)
{
    __shared__ __align__(16) _Float16 Ash[128][40];
    __shared__ __align__(16) _Float16 Bsh[128][40];

    const int t = threadIdx.x;
    const int r0 = blockIdx.x * 128;
    const int n0 = blockIdx.y * 128;
    const int MperD = BB * CT;
    const int d = r0 / MperD;

    const int srow = t >> 2;
    const int koff = (t & 3) * 8;

    auto xrowptr = [&](int r) -> const _Float16* {
        int rd = r - d * MperD;
        int b = rd / CT;
        int tl = rd - b * CT;
        int tsrc = d ? (TT - 1 - (c0 + tl)) : (c0 + tl);
        return x16 + ((size_t)b * TT + tsrc) * FF;
    };
    const _Float16* ap0 = xrowptr(r0 + srow);
    const _Float16* ap1 = xrowptr(r0 + 64 + srow);
    const _Float16* wp0 = WT + (size_t)(d * NZ + n0 + srow) * FF;
    const _Float16* wp1 = wp0 + (size_t)64 * FF;

    const int lane = t & 63;
    const int w = t >> 6;
    const int wm = w >> 1, wn = w & 1;
    const int l15 = lane & 15;
    const int kq = (lane >> 4) * 8;

    f32x4 acc[4][4];
#pragma unroll
    for (int i = 0; i < 4; ++i)
#pragma unroll
        for (int j = 0; j < 4; ++j) acc[i][j] = (f32x4)0.f;

    for (int ks = 0; ks < FF / 32; ++ks) {
        const int k0 = ks * 32;
        uint4 av0 = *(const uint4*)(ap0 + k0 + koff);
        uint4 av1 = *(const uint4*)(ap1 + k0 + koff);
        uint4 bv0 = *(const uint4*)(wp0 + k0 + koff);
        uint4 bv1 = *(const uint4*)(wp1 + k0 + koff);
        __syncthreads();
        *(uint4*)&Ash[srow][koff]      = av0;
        *(uint4*)&Ash[64 + srow][koff] = av1;
        *(uint4*)&Bsh[srow][koff]      = bv0;
        *(uint4*)&Bsh[64 + srow][koff] = bv1;
        __syncthreads();

        half8 af[4], bfr[4];
#pragma unroll
        for (int mf = 0; mf < 4; ++mf)
            af[mf] = *(const half8*)&Ash[wm * 64 + mf * 16 + l15][kq];
#pragma unroll
        for (int nf = 0; nf < 4; ++nf)
            bfr[nf] = *(const half8*)&Bsh[wn * 64 + nf * 16 + l15][kq];
#pragma unroll
        for (int mf = 0; mf < 4; ++mf)
#pragma unroll
            for (int nf = 0; nf < 4; ++nf)
                acc[mf][nf] = __builtin_amdgcn_mfma_f32_16x16x32_f16(
                    af[mf], bfr[nf], acc[mf][nf], 0, 0, 0);
    }

    const float* bd = d ? bb : bf;
    const int rbase = r0 + wm * 64;
    const int cbase = n0 + wn * 64;
#pragma unroll
    for (int nf = 0; nf < 4; ++nf) {
        const int cc = cbase + nf * 16 + l15;
        const float bia = bd[cc];
#pragma unroll
        for (int mf = 0; mf < 4; ++mf) {
#pragma unroll
            for (int rg = 0; rg < 4; ++rg) {
                int rr = rbase + mf * 16 + (lane >> 4) * 4 + rg;
                xz16[(size_t)rr * NZ + cc] = (_Float16)(acc[mf][nf][rg] + bia);
            }
        }
    }
}

// ---------------------------------------------------------------------------
// Split-chain recurrence v4: 256 blocks; beta: jh = beta>>7, chain = beta&127,
// partner = beta^128. Since 128 % 8 == 0, partner blocks land on the SAME XCD
// under round-robin dispatch (bid%8), so the h exchange goes through the
// shared per-XCD L2 (~200cyc store-to-load) instead of the MALL (~600-900).
// Correctness does not depend on the placement heuristic (falls back to MALL).
//
// U (j-half) fully register-resident. s-group (128 thr) = k-quarter.
// own  = s-groups whose k-range is this block's own h-half (locally produced).
// isx  = one partner-consuming, NON-publisher s-group: finalizes the exchange.
//
// Iteration tl consumes h_{c0+tl} and produces h_{c0+tl+1}:
//   ph1: own dots (need no partner data) || isx: spin for tag c0+tl (tl>0)
//   bar1 (lgkm only)
//   ph2: partner-half dots
//   bar2
//   ph3: s==0 reduce+gates+publish(tag step)+own hsh+out + xz prefetch
//        isx: sample next tag's word (prefetch)
//   bar3
// Wait is strictly for the PREVIOUS step's publish -> deadlock-free by
// induction (tl=0 needs no exchange: both halves loaded from hstate).
// Parity slot (tag&1): publish of tag T overwrites T-2, provably consumed.
// Raw lgkm-barriers keep the prefetch loads in flight across phases.
// ---------------------------------------------------------------------------
__device__ __forceinline__ float sigm_f(float xv)
{
    return 1.0f / (1.0f + __expf(-xv));
}
__device__ __forceinline__ float tanh_f(float xv)
{
    return 2.0f / (1.0f + __expf(-2.0f * xv)) - 1.0f;
}

__global__ __launch_bounds__(512, 2) void enc_lstm_split(
    const _Float16* __restrict__ xz16, const uint4* __restrict__ Upkr2,
    float* __restrict__ hstate, float* __restrict__ cstate,
    unsigned int* __restrict__ hbuf,
    float* __restrict__ out, int c0, int CT)
{
    extern __shared__ char smem2[];
    float4*    parts = (float4*)smem2;                 // 4*128*16 = 8192 B
    _Float16*  hsh   = (_Float16*)(smem2 + 8192);      // 512 B
    uint4*     hshq  = (uint4*)hsh;

    const int t  = threadIdx.x;
    const int s  = t >> 7;          // k-quarter 0..3
    const int jl = t & 127;
    const int beta = blockIdx.x;
    const int jh = beta >> 7;                          // j-half
    const int c  = beta & 127;                         // chain 0..127
    const int d  = c >> 6;
    const int b  = c & 63;
    const int j  = jh * 128 + jl;
    const int partner = beta ^ 128;                    // same XCD under %8 rr
    const bool own = ((s >> 1) == jh);    // k-range uses own h-half
    const bool isx = (s == (jh ? 1 : 2)); // exchange group (partner-consuming, non-publisher)

    // ---- persistent U: 32 k2-pairs x 4 gates, register-resident ----
    const uint4* Uq = Upkr2 + ((size_t)d * 128 + s * 32) * 256 + j;
    f16x2 ureg[32][4];
#pragma unroll
    for (int m = 0; m < 32; ++m) {
        uint4 qv = Uq[(size_t)m * 256];
        ureg[m][0] = bc16(qv.x);
        ureg[m][1] = bc16(qv.y);
        ureg[m][2] = bc16(qv.z);
        ureg[m][3] = bc16(qv.w);
    }

    // ---- state init ----
    float cr = 0.f, hn = 0.f;
    if (s == 0) cr = cstate[(size_t)c * UU + j];
    if (t < 256) hsh[t] = (_Float16)hstate[(size_t)c * UU + t];
    __syncthreads();

    const _Float16* xzrow = xz16 + (size_t)c * CT * NZ;
    float* outb = out + (size_t)b * TT * (2 * UU) + d * UU;

    // ---- pre-loop prefetches ----
    unsigned short xp0 = 0, xp1 = 0, xp2 = 0, xp3 = 0;
    if (s == 0) {
        const unsigned short* p = (const unsigned short*)xzrow + j;
        xp0 = p[0]; xp1 = p[256]; xp2 = p[512]; xp3 = p[768];
    }
    unsigned int pref = 0;   // tag 0 never matches a real htag

    auto dot4 = [&](float& a0, float& a1, float& a2, float& a3) {
#pragma unroll
        for (int r = 0; r < 8; ++r) {
            uint4 hq = hshq[s * 8 + r];            // broadcast read
            f16x2 hw[4] = {bc16(hq.x), bc16(hq.y), bc16(hq.z), bc16(hq.w)};
#pragma unroll
            for (int q = 0; q < 4; ++q) {
                const int m = r * 4 + q;
                a0 = __builtin_amdgcn_fdot2(hw[q], ureg[m][0], a0, false);
                a1 = __builtin_amdgcn_fdot2(hw[q], ureg[m][1], a1, false);
                a2 = __builtin_amdgcn_fdot2(hw[q], ureg[m][2], a2, false);
                a3 = __builtin_amdgcn_fdot2(hw[q], ureg[m][3], a3, false);
            }
        }
    };

    for (int tl = 0; tl < CT; ++tl) {
        const int step = c0 + tl + 1;   // h produced this iteration
        const int htag = c0 + tl;       // partner h consumed this iteration

        // ---- phase 1: own-half dots || exchange finalize ----
        if (own) {
            float a0 = 0.f, a1 = 0.f, a2 = 0.f, a3 = 0.f;
            dot4(a0, a1, a2, a3);
            parts[s * 128 + jl] = make_float4(a0, a1, a2, a3);
        }
        if (isx && tl > 0) {
            const unsigned int* pp =
                &hbuf[((size_t)(htag & 1) * 256 + partner) * 128 + jl];
            unsigned int v = pref;
            while ((v >> 16) != (unsigned int)htag)   // tight poll (L2-local)
                v = ld_u32_rlx(pp);
            hsh[(1 - jh) * 128 + jl] =
                __builtin_bit_cast(_Float16, (unsigned short)(v & 0xffffu));
        }
        bar_lgkm();                                // bar1: partner h in hsh

        // ---- phase 2: partner-half dots ----
        if (!own) {
            float a0 = 0.f, a1 = 0.f, a2 = 0.f, a3 = 0.f;
            dot4(a0, a1, a2, a3);
            parts[s * 128 + jl] = make_float4(a0, a1, a2, a3);
        }
        bar_lgkm();                                // bar2: all partials ready

        // ---- phase 3: gates + publish (s==0) ; prefetch sample (isx) ----
        if (s == 0) {
            float4 p0 = parts[jl], p1 = parts[128 + jl];
            float4 p2 = parts[256 + jl], p3 = parts[384 + jl];
            float zi = p0.x + p1.x + p2.x + p3.x
                     + (float)__builtin_bit_cast(_Float16, xp0);
            float zf = p0.y + p1.y + p2.y + p3.y
                     + (float)__builtin_bit_cast(_Float16, xp1);
            float zg = p0.z + p1.z + p2.z + p3.z
                     + (float)__builtin_bit_cast(_Float16, xp2);
            float zo = p0.w + p1.w + p2.w + p3.w
                     + (float)__builtin_bit_cast(_Float16, xp3);
            float ig = sigm_f(zi), fg = sigm_f(zf), gg = tanh_f(zg), og = sigm_f(zo);
            cr = fg * cr + ig * gg;
            hn = og * tanh_f(cr);
            _Float16 h16 = (_Float16)hn;
            // tagged publish first (partner consumes it next iteration)
            st_u32_rlx(&hbuf[((size_t)(step & 1) * 256 + beta) * 128 + jl],
                       ((unsigned int)step << 16)
                       | (unsigned int)__builtin_bit_cast(unsigned short, h16));
            hsh[j] = h16;
            int tsrc = d ? (TT - 1 - (c0 + tl)) : (c0 + tl);
            outb[(size_t)tsrc * (2 * UU) + j] = hn;
            // prefetch next step's xz (stays in flight across raw barriers)
            int tn = (tl + 1 < CT) ? tl + 1 : tl;
            const unsigned short* pn =
                (const unsigned short*)(xzrow + (size_t)tn * NZ) + j;
            xp0 = pn[0]; xp1 = pn[256]; xp2 = pn[512]; xp3 = pn[768];
        }
        if (isx) {
            // sample the word for next iteration's htag (= step)
            pref = ld_u32_rlx(&hbuf[((size_t)(step & 1) * 256 + partner) * 128 + jl]);
        }
        bar_lgkm();                                // bar3: own hsh half updated
    }

    if (s == 0) {
        hstate[(size_t)c * UU + j] = hn;
        cstate[(size_t)c * UU + j] = cr;
    }
}

// ---------------------------------------------------------------------------
// Final h/c copy into d_out tail sections
// ---------------------------------------------------------------------------
__global__ __launch_bounds__(256) void enc_final(
    const float* __restrict__ hstate, const float* __restrict__ cstate,
    float* __restrict__ out)
{
    int idx = blockIdx.x * 256 + threadIdx.x;
    if (idx >= 2 * BB * UU) return;
    int d = idx / (BB * UU);
    int rem = idx - d * (BB * UU);
    int b = rem / UU;
    int j = rem - b * UU;
    size_t OUT_H = (size_t)BB * TT * (2 * UU);
    size_t HSZ = (size_t)BB * (2 * UU);
    out[OUT_H + (size_t)b * (2 * UU) + d * UU + j] = hstate[idx];
    out[OUT_H + HSZ + (size_t)b * (2 * UU) + d * UU + j] = cstate[idx];
}

// ---------------------------------------------------------------------------
extern "C" void kernel_launch(void* const* d_in, const int* in_sizes, int n_in,
                              void* d_out, int out_size, void* d_ws, size_t ws_size,
                              hipStream_t stream)
{
    const float* x  = (const float*)d_in[0];
    const float* Wf = (const float*)d_in[1];
    const float* Uf = (const float*)d_in[2];
    const float* bf = (const float*)d_in[3];
    const float* Wb = (const float*)d_in[4];
    const float* Ub = (const float*)d_in[5];
    const float* bb = (const float*)d_in[6];
    float* out = (float*)d_out;

    const size_t x16_bytes   = (size_t)BB * TT * FF * 2;             // 64 MiB
    const size_t wt_bytes    = (size_t)2 * NZ * FF * 2;              // 2 MiB
    const size_t upk_bytes   = (size_t)2 * 128 * 256 * sizeof(uint4);// 1 MiB
    const size_t state_bytes = (size_t)2 * BB * UU * sizeof(float);  // 128 KiB each
    const size_t hbuf_bytes  = (size_t)2 * 256 * 128 * 4;            // 256 KiB
    const size_t fixed = x16_bytes + wt_bytes + upk_bytes + 2 * state_bytes
                       + hbuf_bytes;

    int CT = TT;
    while (CT > 8) {
        size_t need = fixed + (size_t)2 * BB * CT * NZ * 2;
        if (need <= ws_size) break;
        CT >>= 1;
    }

    char* wsb = (char*)d_ws;
    _Float16* x16 = (_Float16*)wsb;
    _Float16* WT  = (_Float16*)(wsb + x16_bytes);
    uint4* Upkr2  = (uint4*)(wsb + x16_bytes + wt_bytes);
    float* hstate = (float*)(wsb + x16_bytes + wt_bytes + upk_bytes);
    float* cstate = hstate + 2 * BB * UU;
    unsigned int* hbuf = (unsigned int*)(wsb + x16_bytes + wt_bytes + upk_bytes
                                         + 2 * state_bytes);
    _Float16* xz16 = (_Float16*)(wsb + fixed);

    (void)hipFuncSetAttribute(reinterpret_cast<const void*>(enc_lstm_split),
                              hipFuncAttributeMaxDynamicSharedMemorySize,
                              (int)LSTM_SHBYTES);

    enc_cast_x<<<4096, 256, 0, stream>>>(x, x16, BB * TT * FF / 4);
    enc_cast_wt<<<dim3(8, 16, 2), 256, 0, stream>>>(Wf, Wb, WT);
    enc_pack_u16v2<<<(2 * 128 * 256 + 255) / 256, 256, 0, stream>>>(Uf, Ub, Upkr2);
    enc_zero<<<(2 * 2 * BB * UU + 255) / 256, 256, 0, stream>>>(hstate, 2 * 2 * BB * UU);

    for (int c0 = 0; c0 < TT; c0 += CT) {
        dim3 ggrid((2 * BB * CT) / 128, NZ / 128);
        enc_gemm16<<<ggrid, 256, 0, stream>>>(x16, WT, bf, bb, xz16, c0, CT);
        enc_lstm_split<<<256, 512, LSTM_SHBYTES, stream>>>(
            xz16, Upkr2, hstate, cstate, hbuf, out, c0, CT);
    }
    enc_final<<<(2 * BB * UU + 255) / 256, 256, 0, stream>>>(hstate, cstate, out);
}